// Round 1
// baseline (3185.629 us; speedup 1.0000x reference)
//
#include <hip/hip_runtime.h>
#include <math.h>

#define N_NODES 204800
#define N_EDGES 600000
#define N_GRAPH 3200
#define H 128
#define NF 16
#define EF 5
#define GF 8
#define LAYERS 6
#define SEG 64
#define EPSV 1e-5f

// ---------------- K1: h = x @ node_w + node_b ----------------
__global__ __launch_bounds__(256) void k_init_h(
    const float* __restrict__ x, const float* __restrict__ node_w,
    const float* __restrict__ node_b, float* __restrict__ h)
{
    int idx = blockIdx.x * 256 + threadIdx.x;   // n*128 + c
    int n = idx >> 7, c = idx & 127;
    float acc = node_b[c];
    const float* xr = x + n * NF;
#pragma unroll
    for (int k = 0; k < NF; ++k) acc += xr[k] * node_w[k * H + c];
    h[idx] = acc;
}

// ---------------- K3: msg = h[src]*ea ; agg[dst] += msg ----------------
__global__ __launch_bounds__(256) void k_msg(
    const int* __restrict__ ei, const float* __restrict__ eattr,
    const float* __restrict__ edge_w, const float* __restrict__ edge_b,
    const float* __restrict__ h, float* __restrict__ agg)
{
    int tid = threadIdx.x;
    int e = blockIdx.x * 2 + (tid >> 7);
    int c = tid & 127;
    if (e >= N_EDGES) return;
    int s = ei[e], d = ei[N_EDGES + e];
    const float* ar = eattr + (size_t)e * EF;
    float ea = edge_b[c];
#pragma unroll
    for (int k = 0; k < EF; ++k) ea += ar[k] * edge_w[k * H + c];
    float val = h[(size_t)s * H + c] * ea;
    atomicAdd(&agg[(size_t)d * H + c], val);
}

// ---------------- K4: h2 = agg@rel_w + h@root_w + rel_b ; col sums ----------------
// block = 256 threads, tile = 64 rows x 128 cols, thread = 4 rows x 8 cols
__global__ __launch_bounds__(256) void k_gemm_bn(
    const float* __restrict__ agg, const float* __restrict__ h,
    const float* __restrict__ relw, const float* __restrict__ rootw,
    const float* __restrict__ relb,
    float* __restrict__ h2, float* __restrict__ stats)
{
    __shared__ float As[64][33];    // 64 rows x 32 k (+1 pad)
    __shared__ float Ws[32][132];   // 32 k x 128 cols (+4 pad)
    int tid = threadIdx.x;
    int n0 = blockIdx.x * 64;
    int ct = tid & 15, rg = tid >> 4;
    int c0 = ct * 8;

    float acc[4][8];
    {
        float bias[8];
#pragma unroll
        for (int j = 0; j < 8; ++j) bias[j] = relb[c0 + j];
#pragma unroll
        for (int r = 0; r < 4; ++r)
#pragma unroll
            for (int j = 0; j < 8; ++j) acc[r][j] = bias[j];
    }

    const int lr = tid >> 2;            // A load row 0..63
    const int lk = (tid & 3) * 8;       // A load k offset
    const int wk = tid >> 3;            // W load k 0..31
    const int wc = (tid & 7) * 16;      // W load col offset

    for (int t = 0; t < 8; ++t) {
        const float* Asrc = (t < 4) ? agg : h;
        const float* Wsrc = (t < 4) ? relw : rootw;
        int k0 = (t & 3) * 32;
        const float4* ap = (const float4*)(Asrc + (size_t)(n0 + lr) * H + k0 + lk);
        float4 a0 = ap[0], a1 = ap[1];
        const float4* wp = (const float4*)(Wsrc + (size_t)(k0 + wk) * H + wc);
        float4 w0 = wp[0], w1 = wp[1], w2 = wp[2], w3 = wp[3];
        __syncthreads();
        As[lr][lk + 0] = a0.x; As[lr][lk + 1] = a0.y; As[lr][lk + 2] = a0.z; As[lr][lk + 3] = a0.w;
        As[lr][lk + 4] = a1.x; As[lr][lk + 5] = a1.y; As[lr][lk + 6] = a1.z; As[lr][lk + 7] = a1.w;
        *(float4*)&Ws[wk][wc + 0]  = w0;
        *(float4*)&Ws[wk][wc + 4]  = w1;
        *(float4*)&Ws[wk][wc + 8]  = w2;
        *(float4*)&Ws[wk][wc + 12] = w3;
        __syncthreads();
#pragma unroll
        for (int k = 0; k < 32; ++k) {
            float a0v = As[rg * 4 + 0][k];
            float a1v = As[rg * 4 + 1][k];
            float a2v = As[rg * 4 + 2][k];
            float a3v = As[rg * 4 + 3][k];
            float4 wv0 = *(const float4*)&Ws[k][c0];
            float4 wv1 = *(const float4*)&Ws[k][c0 + 4];
            acc[0][0] += a0v * wv0.x; acc[0][1] += a0v * wv0.y; acc[0][2] += a0v * wv0.z; acc[0][3] += a0v * wv0.w;
            acc[0][4] += a0v * wv1.x; acc[0][5] += a0v * wv1.y; acc[0][6] += a0v * wv1.z; acc[0][7] += a0v * wv1.w;
            acc[1][0] += a1v * wv0.x; acc[1][1] += a1v * wv0.y; acc[1][2] += a1v * wv0.z; acc[1][3] += a1v * wv0.w;
            acc[1][4] += a1v * wv1.x; acc[1][5] += a1v * wv1.y; acc[1][6] += a1v * wv1.z; acc[1][7] += a1v * wv1.w;
            acc[2][0] += a2v * wv0.x; acc[2][1] += a2v * wv0.y; acc[2][2] += a2v * wv0.z; acc[2][3] += a2v * wv0.w;
            acc[2][4] += a2v * wv1.x; acc[2][5] += a2v * wv1.y; acc[2][6] += a2v * wv1.z; acc[2][7] += a2v * wv1.w;
            acc[3][0] += a3v * wv0.x; acc[3][1] += a3v * wv0.y; acc[3][2] += a3v * wv0.z; acc[3][3] += a3v * wv0.w;
            acc[3][4] += a3v * wv1.x; acc[3][5] += a3v * wv1.y; acc[3][6] += a3v * wv1.z; acc[3][7] += a3v * wv1.w;
        }
    }

    // write h2 (NOTE: h2 aliases agg; this block's rows were fully read above)
#pragma unroll
    for (int r = 0; r < 4; ++r) {
        size_t row = (size_t)(n0 + rg * 4 + r);
        *(float4*)(h2 + row * H + c0)     = make_float4(acc[r][0], acc[r][1], acc[r][2], acc[r][3]);
        *(float4*)(h2 + row * H + c0 + 4) = make_float4(acc[r][4], acc[r][5], acc[r][6], acc[r][7]);
    }

    // BN column sums: reduce 4 local rows, then across 16 row-groups via LDS
    float ps[8], pq[8];
#pragma unroll
    for (int j = 0; j < 8; ++j) {
        ps[j] = acc[0][j] + acc[1][j] + acc[2][j] + acc[3][j];
        pq[j] = acc[0][j]*acc[0][j] + acc[1][j]*acc[1][j] + acc[2][j]*acc[2][j] + acc[3][j]*acc[3][j];
    }
    __syncthreads();                 // done with As/Ws; reuse As as Red[16][128]
    float* Red = &As[0][0];
#pragma unroll
    for (int j = 0; j < 8; ++j) Red[rg * 128 + c0 + j] = ps[j];
    __syncthreads();
    if (tid < 128) {
        float s = 0.f;
#pragma unroll
        for (int g = 0; g < 16; ++g) s += Red[g * 128 + tid];
        atomicAdd(&stats[tid], s);
    }
    __syncthreads();
#pragma unroll
    for (int j = 0; j < 8; ++j) Red[rg * 128 + c0 + j] = pq[j];
    __syncthreads();
    if (tid < 128) {
        float s = 0.f;
#pragma unroll
        for (int g = 0; g < 16; ++g) s += Red[g * 128 + tid];
        atomicAdd(&stats[H + tid], s);
    }
}

// ---------------- K5: BN stats -> scale/shift, rezero accumulators ----------------
__global__ void k_bn_stats(float* stats, const float* __restrict__ gamma,
                           const float* __restrict__ beta)
{
    int c = threadIdx.x;
    float s = stats[c], sq = stats[H + c];
    float mean = s / (float)N_NODES;
    float var = sq / (float)N_NODES - mean * mean;
    var = fmaxf(var, 0.f);
    float scale = gamma[c] * rsqrtf(var + EPSV);
    float shift = beta[c] - mean * scale;
    stats[2 * H + c] = scale;
    stats[3 * H + c] = shift;
    stats[c] = 0.f;
    stats[H + c] = 0.f;
}

// ---------------- K6: h = relu(h2*scale + shift + h) ----------------
__global__ __launch_bounds__(256) void k_bn_apply(
    const float* __restrict__ h2, const float* __restrict__ stats,
    float* __restrict__ h)
{
    size_t idx = (size_t)blockIdx.x * 256 + threadIdx.x;
    size_t base = idx * 4;
    int c = (int)(base & 127);
    float4 v = *(const float4*)(h2 + base);
    float4 hv = *(const float4*)(h + base);
    const float* sc = stats + 2 * H + c;
    const float* sh = stats + 3 * H + c;
    float4 o;
    o.x = fmaxf(v.x * sc[0] + sh[0] + hv.x, 0.f);
    o.y = fmaxf(v.y * sc[1] + sh[1] + hv.y, 0.f);
    o.z = fmaxf(v.z * sc[2] + sh[2] + hv.z, 0.f);
    o.w = fmaxf(v.w * sc[3] + sh[3] + hv.w, 0.f);
    *(float4*)(h + base) = o;
}

// ---------------- K7: gate = relu(h@W1+b1)@w2 + b2 ----------------
__global__ __launch_bounds__(256) void k_gate(
    const float* __restrict__ h, const float* __restrict__ w1,
    const float* __restrict__ b1, const float* __restrict__ w2,
    const float* __restrict__ b2, float* __restrict__ gate)
{
    __shared__ float As[64][33];
    __shared__ float Ws[32][132];
    int tid = threadIdx.x;
    int n0 = blockIdx.x * 64;
    int ct = tid & 15, rg = tid >> 4;
    int c0 = ct * 8;

    float acc[4][8];
    {
        float bias[8];
#pragma unroll
        for (int j = 0; j < 8; ++j) bias[j] = b1[c0 + j];
#pragma unroll
        for (int r = 0; r < 4; ++r)
#pragma unroll
            for (int j = 0; j < 8; ++j) acc[r][j] = bias[j];
    }

    const int lr = tid >> 2;
    const int lk = (tid & 3) * 8;
    const int wk = tid >> 3;
    const int wc = (tid & 7) * 16;

    for (int t = 0; t < 4; ++t) {
        int k0 = t * 32;
        const float4* ap = (const float4*)(h + (size_t)(n0 + lr) * H + k0 + lk);
        float4 a0 = ap[0], a1 = ap[1];
        const float4* wp = (const float4*)(w1 + (size_t)(k0 + wk) * H + wc);
        float4 w0 = wp[0], w1v = wp[1], w2v_ = wp[2], w3 = wp[3];
        __syncthreads();
        As[lr][lk + 0] = a0.x; As[lr][lk + 1] = a0.y; As[lr][lk + 2] = a0.z; As[lr][lk + 3] = a0.w;
        As[lr][lk + 4] = a1.x; As[lr][lk + 5] = a1.y; As[lr][lk + 6] = a1.z; As[lr][lk + 7] = a1.w;
        *(float4*)&Ws[wk][wc + 0]  = w0;
        *(float4*)&Ws[wk][wc + 4]  = w1v;
        *(float4*)&Ws[wk][wc + 8]  = w2v_;
        *(float4*)&Ws[wk][wc + 12] = w3;
        __syncthreads();
#pragma unroll
        for (int k = 0; k < 32; ++k) {
            float a0v = As[rg * 4 + 0][k];
            float a1v = As[rg * 4 + 1][k];
            float a2v = As[rg * 4 + 2][k];
            float a3v = As[rg * 4 + 3][k];
            float4 wv0 = *(const float4*)&Ws[k][c0];
            float4 wv1 = *(const float4*)&Ws[k][c0 + 4];
            acc[0][0] += a0v * wv0.x; acc[0][1] += a0v * wv0.y; acc[0][2] += a0v * wv0.z; acc[0][3] += a0v * wv0.w;
            acc[0][4] += a0v * wv1.x; acc[0][5] += a0v * wv1.y; acc[0][6] += a0v * wv1.z; acc[0][7] += a0v * wv1.w;
            acc[1][0] += a1v * wv0.x; acc[1][1] += a1v * wv0.y; acc[1][2] += a1v * wv0.z; acc[1][3] += a1v * wv0.w;
            acc[1][4] += a1v * wv1.x; acc[1][5] += a1v * wv1.y; acc[1][6] += a1v * wv1.z; acc[1][7] += a1v * wv1.w;
            acc[2][0] += a2v * wv0.x; acc[2][1] += a2v * wv0.y; acc[2][2] += a2v * wv0.z; acc[2][3] += a2v * wv0.w;
            acc[2][4] += a2v * wv1.x; acc[2][5] += a2v * wv1.y; acc[2][6] += a2v * wv1.z; acc[2][7] += a2v * wv1.w;
            acc[3][0] += a3v * wv0.x; acc[3][1] += a3v * wv0.y; acc[3][2] += a3v * wv0.z; acc[3][3] += a3v * wv0.w;
            acc[3][4] += a3v * wv1.x; acc[3][5] += a3v * wv1.y; acc[3][6] += a3v * wv1.z; acc[3][7] += a3v * wv1.w;
        }
    }

    // relu + dot with w2, reduce across 16 col-threads
    float w2loc[8];
#pragma unroll
    for (int j = 0; j < 8; ++j) w2loc[j] = w2[c0 + j];
    float gsum[4];
#pragma unroll
    for (int r = 0; r < 4; ++r) {
        float s = 0.f;
#pragma unroll
        for (int j = 0; j < 8; ++j) s += fmaxf(acc[r][j], 0.f) * w2loc[j];
        gsum[r] = s;
    }
    __syncthreads();
    float* Red = &As[0][0];   // need 16*64 floats
#pragma unroll
    for (int r = 0; r < 4; ++r) Red[ct * 64 + rg * 4 + r] = gsum[r];
    __syncthreads();
    if (tid < 64) {
        float s = 0.f;
#pragma unroll
        for (int t = 0; t < 16; ++t) s += Red[t * 64 + tid];
        gate[n0 + tid] = s + b2[0];
    }
}

// ---------------- K8: per-graph softmax over 64 contiguous nodes + weighted pool ----------------
__global__ __launch_bounds__(64) void k_pool(
    const float* __restrict__ gate, const float* __restrict__ h,
    float* __restrict__ pooled)
{
    int g = blockIdx.x, l = threadIdx.x;
    float gt = gate[g * SEG + l];
    float m = gt;
#pragma unroll
    for (int off = 32; off >= 1; off >>= 1) m = fmaxf(m, __shfl_xor(m, off));
    float e = expf(gt - m);
    float s = e;
#pragma unroll
    for (int off = 32; off >= 1; off >>= 1) s += __shfl_xor(s, off);
    float alpha = e / s;
    __shared__ float al[SEG];
    al[l] = alpha;
    __syncthreads();
    float p0 = 0.f, p1 = 0.f;
    const float* hb = h + (size_t)g * SEG * H;
    for (int j = 0; j < SEG; ++j) {
        float a = al[j];
        p0 += a * hb[(size_t)j * H + l];
        p1 += a * hb[(size_t)j * H + 64 + l];
    }
    pooled[(size_t)g * H + l] = p0;
    pooled[(size_t)g * H + 64 + l] = p1;
}

// ---------------- K9: global_embedding = [pooled, gf] @ gi_w + gi_b ----------------
__global__ __launch_bounds__(128) void k_final(
    const float* __restrict__ pooled, const float* __restrict__ gfeat,
    const float* __restrict__ gf_w, const float* __restrict__ gf_b,
    const float* __restrict__ gi_w, const float* __restrict__ gi_b,
    float* __restrict__ out)
{
    int g = blockIdx.x, c = threadIdx.x;
    __shared__ float prow[H], gfs[H];
    prow[c] = pooled[(size_t)g * H + c];
    float gv = gf_b[c];
    const float* gr = gfeat + (size_t)g * GF;
#pragma unroll
    for (int k = 0; k < GF; ++k) gv += gr[k] * gf_w[k * H + c];
    gfs[c] = gv;
    __syncthreads();
    float acc = gi_b[c];
    for (int k = 0; k < H; ++k) acc += prow[k] * gi_w[k * H + c];
    for (int k = 0; k < H; ++k) acc += gfs[k] * gi_w[(H + k) * H + c];
    out[(size_t)N_NODES * H + (size_t)g * H + c] = acc;
}

extern "C" void kernel_launch(void* const* d_in, const int* in_sizes, int n_in,
                              void* d_out, int out_size, void* d_ws, size_t ws_size,
                              hipStream_t stream)
{
    const float* x       = (const float*)d_in[0];
    const int*   ei      = (const int*)d_in[1];
    const float* eattr   = (const float*)d_in[2];
    const float* gfeat   = (const float*)d_in[3];
    // d_in[4] = batch (unused; batch[n] == n/64)
    const float* node_w  = (const float*)d_in[5];
    const float* node_b  = (const float*)d_in[6];
    const float* edge_w  = (const float*)d_in[7];
    const float* edge_b  = (const float*)d_in[8];
    const float* rel_w   = (const float*)d_in[9];
    const float* rel_b   = (const float*)d_in[10];
    const float* root_w  = (const float*)d_in[11];
    const float* bn_g    = (const float*)d_in[12];
    const float* bn_b    = (const float*)d_in[13];
    const float* gate_w1 = (const float*)d_in[14];
    const float* gate_b1 = (const float*)d_in[15];
    const float* gate_w2 = (const float*)d_in[16];
    const float* gate_b2 = (const float*)d_in[17];
    const float* gf_w    = (const float*)d_in[18];
    const float* gf_b    = (const float*)d_in[19];
    const float* gi_w    = (const float*)d_in[20];
    const float* gi_b    = (const float*)d_in[21];

    float* h      = (float*)d_out;                       // [N,H] output 0, live h
    float* out    = (float*)d_out;
    float* agg    = (float*)d_ws;                        // [N,H]; h2 aliases agg (safe, see K4)
    float* h2     = agg;
    float* stats  = agg + (size_t)N_NODES * H;           // 512 floats
    float* gate   = stats + 512;                         // [N]
    float* pooled = gate + N_NODES;                      // [G,H]

    k_init_h<<<N_NODES * H / 256, 256, 0, stream>>>(x, node_w, node_b, h);
    hipMemsetAsync(stats, 0, 512 * sizeof(float), stream);

    for (int i = 0; i < LAYERS; ++i) {
        hipMemsetAsync(agg, 0, (size_t)N_NODES * H * sizeof(float), stream);
        k_msg<<<N_EDGES / 2, 256, 0, stream>>>(ei, eattr, edge_w, edge_b, h, agg);
        k_gemm_bn<<<N_NODES / 64, 256, 0, stream>>>(
            agg, h, rel_w + (size_t)i * H * H, root_w + (size_t)i * H * H,
            rel_b + (size_t)i * H, h2, stats);
        k_bn_stats<<<1, 128, 0, stream>>>(stats, bn_g + (size_t)i * H, bn_b + (size_t)i * H);
        k_bn_apply<<<N_NODES * H / 4 / 256, 256, 0, stream>>>(h2, stats, h);
    }

    k_gate<<<N_NODES / 64, 256, 0, stream>>>(h, gate_w1, gate_b1, gate_w2, gate_b2, gate);
    k_pool<<<N_GRAPH, SEG, 0, stream>>>(gate, h, pooled);
    k_final<<<N_GRAPH, H, 0, stream>>>(pooled, gfeat, gf_w, gf_b, gi_w, gi_b, out);
}

// Round 2
// 2632.115 us; speedup vs baseline: 1.2103x; 1.2103x over previous
//
#include <hip/hip_runtime.h>
#include <math.h>

#define N_NODES 204800
#define N_EDGES 600000
#define N_GRAPH 3200
#define H 128
#define NF 16
#define EF 5
#define GF 8
#define LAYERS 6
#define SEG 64
#define EPSV 1e-5f
#define NB_SCAN 800   // N_NODES / 256

// ---------------- K1: h = x @ node_w + node_b ----------------
__global__ __launch_bounds__(256) void k_init_h(
    const float* __restrict__ x, const float* __restrict__ node_w,
    const float* __restrict__ node_b, float* __restrict__ h)
{
    int idx = blockIdx.x * 256 + threadIdx.x;   // n*128 + c
    int n = idx >> 7, c = idx & 127;
    float acc = node_b[c];
    const float* xr = x + n * NF;
#pragma unroll
    for (int k = 0; k < NF; ++k) acc += xr[k] * node_w[k * H + c];
    h[idx] = acc;
}

// ---------------- CSR build: deg -> scan -> scatter ----------------
__global__ __launch_bounds__(256) void k_deg(const int* __restrict__ ei, int* __restrict__ deg)
{
    int e = blockIdx.x * 256 + threadIdx.x;
    if (e < N_EDGES) atomicAdd(&deg[ei[N_EDGES + e]], 1);
}

__global__ __launch_bounds__(256) void k_scan1(
    const int* __restrict__ deg, int* __restrict__ rowtmp, int* __restrict__ bsum)
{
    __shared__ int sh[256];
    int t = threadIdx.x;
    int i = blockIdx.x * 256 + t;
    int v = deg[i];
    sh[t] = v;
    __syncthreads();
    for (int off = 1; off < 256; off <<= 1) {
        int a = (t >= off) ? sh[t - off] : 0;
        __syncthreads();
        sh[t] += a;
        __syncthreads();
    }
    rowtmp[i] = sh[t] - v;                 // exclusive
    if (t == 255) bsum[blockIdx.x] = sh[255];
}

__global__ void k_scan2(int* __restrict__ bsum, int* __restrict__ boff)  // 1 block x 256
{
    __shared__ int sh[256];
    __shared__ int carry;
    int t = threadIdx.x;
    if (t == 0) carry = 0;
    __syncthreads();
    for (int base = 0; base < NB_SCAN; base += 256) {
        int i = base + t;
        int v = (i < NB_SCAN) ? bsum[i] : 0;
        sh[t] = v;
        __syncthreads();
        for (int off = 1; off < 256; off <<= 1) {
            int a = (t >= off) ? sh[t - off] : 0;
            __syncthreads();
            sh[t] += a;
            __syncthreads();
        }
        if (i < NB_SCAN) boff[i] = carry + sh[t] - v;
        __syncthreads();
        if (t == 0) carry += sh[255];
        __syncthreads();
    }
}

__global__ __launch_bounds__(256) void k_scan3(
    const int* __restrict__ rowtmp, const int* __restrict__ boff,
    int* __restrict__ rowptr, int* __restrict__ cursor)
{
    int i = blockIdx.x * 256 + threadIdx.x;
    int r = rowtmp[i] + boff[blockIdx.x];
    rowptr[i] = r;
    cursor[i] = r;
    if (i == 0) rowptr[N_NODES] = N_EDGES;
}

__global__ __launch_bounds__(256) void k_scatter(
    const int* __restrict__ ei, int* __restrict__ cursor, int2* __restrict__ pairs)
{
    int e = blockIdx.x * 256 + threadIdx.x;
    if (e >= N_EDGES) return;
    int d = ei[N_EDGES + e];
    int pos = atomicAdd(&cursor[d], 1);
    pairs[pos] = make_int2(ei[e], e);      // (src, edge_id)
}

// ---------------- K3': pull-mode aggregation (atomic-free) ----------------
// agg[n,c] = sum over incoming edges e of h[src_e,c] * (edge_attr[e] @ edge_w + edge_b)[c]
__global__ __launch_bounds__(256) void k_agg(
    const int* __restrict__ rowptr, const int2* __restrict__ pairs,
    const float* __restrict__ eattr,
    const float* __restrict__ edge_w, const float* __restrict__ edge_b,
    const float* __restrict__ h, float* __restrict__ agg)
{
    int tid = threadIdx.x;
    int n = blockIdx.x * 2 + (tid >> 7);
    int c = tid & 127;
    float ew[EF];
#pragma unroll
    for (int k = 0; k < EF; ++k) ew[k] = edge_w[k * H + c];
    float eb = edge_b[c];
    float acc = 0.f;
    int j1 = rowptr[n + 1];
    for (int j = rowptr[n]; j < j1; ++j) {
        int2 p = pairs[j];                          // broadcast across the group
        const float* ar = eattr + (size_t)p.y * EF; // 5 floats, broadcast
        float ea = eb;
#pragma unroll
        for (int k = 0; k < EF; ++k) ea += ar[k] * ew[k];
        acc += h[(size_t)p.x * H + c] * ea;         // coalesced 512B row gather
    }
    agg[(size_t)n * H + c] = acc;
}

// ---------------- K4: h2 = agg@rel_w + h@root_w + rel_b ; col sums ----------------
// block = 256 threads, tile = 64 rows x 128 cols, thread = 4 rows x 8 cols
__global__ __launch_bounds__(256) void k_gemm_bn(
    const float* __restrict__ agg, const float* __restrict__ h,
    const float* __restrict__ relw, const float* __restrict__ rootw,
    const float* __restrict__ relb,
    float* __restrict__ h2, float* __restrict__ stats)
{
    __shared__ float As[64][33];    // 64 rows x 32 k (+1 pad)
    __shared__ float Ws[32][132];   // 32 k x 128 cols (+4 pad)
    int tid = threadIdx.x;
    int n0 = blockIdx.x * 64;
    int ct = tid & 15, rg = tid >> 4;
    int c0 = ct * 8;

    float acc[4][8];
    {
        float bias[8];
#pragma unroll
        for (int j = 0; j < 8; ++j) bias[j] = relb[c0 + j];
#pragma unroll
        for (int r = 0; r < 4; ++r)
#pragma unroll
            for (int j = 0; j < 8; ++j) acc[r][j] = bias[j];
    }

    const int lr = tid >> 2;            // A load row 0..63
    const int lk = (tid & 3) * 8;       // A load k offset
    const int wk = tid >> 3;            // W load k 0..31
    const int wc = (tid & 7) * 16;      // W load col offset

    for (int t = 0; t < 8; ++t) {
        const float* Asrc = (t < 4) ? agg : h;
        const float* Wsrc = (t < 4) ? relw : rootw;
        int k0 = (t & 3) * 32;
        const float4* ap = (const float4*)(Asrc + (size_t)(n0 + lr) * H + k0 + lk);
        float4 a0 = ap[0], a1 = ap[1];
        const float4* wp = (const float4*)(Wsrc + (size_t)(k0 + wk) * H + wc);
        float4 w0 = wp[0], w1 = wp[1], w2 = wp[2], w3 = wp[3];
        __syncthreads();
        As[lr][lk + 0] = a0.x; As[lr][lk + 1] = a0.y; As[lr][lk + 2] = a0.z; As[lr][lk + 3] = a0.w;
        As[lr][lk + 4] = a1.x; As[lr][lk + 5] = a1.y; As[lr][lk + 6] = a1.z; As[lr][lk + 7] = a1.w;
        *(float4*)&Ws[wk][wc + 0]  = w0;
        *(float4*)&Ws[wk][wc + 4]  = w1;
        *(float4*)&Ws[wk][wc + 8]  = w2;
        *(float4*)&Ws[wk][wc + 12] = w3;
        __syncthreads();
#pragma unroll
        for (int k = 0; k < 32; ++k) {
            float a0v = As[rg * 4 + 0][k];
            float a1v = As[rg * 4 + 1][k];
            float a2v = As[rg * 4 + 2][k];
            float a3v = As[rg * 4 + 3][k];
            float4 wv0 = *(const float4*)&Ws[k][c0];
            float4 wv1 = *(const float4*)&Ws[k][c0 + 4];
            acc[0][0] += a0v * wv0.x; acc[0][1] += a0v * wv0.y; acc[0][2] += a0v * wv0.z; acc[0][3] += a0v * wv0.w;
            acc[0][4] += a0v * wv1.x; acc[0][5] += a0v * wv1.y; acc[0][6] += a0v * wv1.z; acc[0][7] += a0v * wv1.w;
            acc[1][0] += a1v * wv0.x; acc[1][1] += a1v * wv0.y; acc[1][2] += a1v * wv0.z; acc[1][3] += a1v * wv0.w;
            acc[1][4] += a1v * wv1.x; acc[1][5] += a1v * wv1.y; acc[1][6] += a1v * wv1.z; acc[1][7] += a1v * wv1.w;
            acc[2][0] += a2v * wv0.x; acc[2][1] += a2v * wv0.y; acc[2][2] += a2v * wv0.z; acc[2][3] += a2v * wv0.w;
            acc[2][4] += a2v * wv1.x; acc[2][5] += a2v * wv1.y; acc[2][6] += a2v * wv1.z; acc[2][7] += a2v * wv1.w;
            acc[3][0] += a3v * wv0.x; acc[3][1] += a3v * wv0.y; acc[3][2] += a3v * wv0.z; acc[3][3] += a3v * wv0.w;
            acc[3][4] += a3v * wv1.x; acc[3][5] += a3v * wv1.y; acc[3][6] += a3v * wv1.z; acc[3][7] += a3v * wv1.w;
        }
    }

    // write h2 (NOTE: h2 aliases agg; this block's rows were fully read above)
#pragma unroll
    for (int r = 0; r < 4; ++r) {
        size_t row = (size_t)(n0 + rg * 4 + r);
        *(float4*)(h2 + row * H + c0)     = make_float4(acc[r][0], acc[r][1], acc[r][2], acc[r][3]);
        *(float4*)(h2 + row * H + c0 + 4) = make_float4(acc[r][4], acc[r][5], acc[r][6], acc[r][7]);
    }

    // BN column sums: reduce 4 local rows, then across 16 row-groups via LDS
    float ps[8], pq[8];
#pragma unroll
    for (int j = 0; j < 8; ++j) {
        ps[j] = acc[0][j] + acc[1][j] + acc[2][j] + acc[3][j];
        pq[j] = acc[0][j]*acc[0][j] + acc[1][j]*acc[1][j] + acc[2][j]*acc[2][j] + acc[3][j]*acc[3][j];
    }
    __syncthreads();                 // done with As/Ws; reuse As as Red[16][128]
    float* Red = &As[0][0];
#pragma unroll
    for (int j = 0; j < 8; ++j) Red[rg * 128 + c0 + j] = ps[j];
    __syncthreads();
    if (tid < 128) {
        float s = 0.f;
#pragma unroll
        for (int g = 0; g < 16; ++g) s += Red[g * 128 + tid];
        atomicAdd(&stats[tid], s);
    }
    __syncthreads();
#pragma unroll
    for (int j = 0; j < 8; ++j) Red[rg * 128 + c0 + j] = pq[j];
    __syncthreads();
    if (tid < 128) {
        float s = 0.f;
#pragma unroll
        for (int g = 0; g < 16; ++g) s += Red[g * 128 + tid];
        atomicAdd(&stats[H + tid], s);
    }
}

// ---------------- K5: BN stats -> scale/shift, rezero accumulators ----------------
__global__ void k_bn_stats(float* stats, const float* __restrict__ gamma,
                           const float* __restrict__ beta)
{
    int c = threadIdx.x;
    float s = stats[c], sq = stats[H + c];
    float mean = s / (float)N_NODES;
    float var = sq / (float)N_NODES - mean * mean;
    var = fmaxf(var, 0.f);
    float scale = gamma[c] * rsqrtf(var + EPSV);
    float shift = beta[c] - mean * scale;
    stats[2 * H + c] = scale;
    stats[3 * H + c] = shift;
    stats[c] = 0.f;
    stats[H + c] = 0.f;
}

// ---------------- K6: h = relu(h2*scale + shift + h) ----------------
__global__ __launch_bounds__(256) void k_bn_apply(
    const float* __restrict__ h2, const float* __restrict__ stats,
    float* __restrict__ h)
{
    size_t idx = (size_t)blockIdx.x * 256 + threadIdx.x;
    size_t base = idx * 4;
    int c = (int)(base & 127);
    float4 v = *(const float4*)(h2 + base);
    float4 hv = *(const float4*)(h + base);
    const float* sc = stats + 2 * H + c;
    const float* sh = stats + 3 * H + c;
    float4 o;
    o.x = fmaxf(v.x * sc[0] + sh[0] + hv.x, 0.f);
    o.y = fmaxf(v.y * sc[1] + sh[1] + hv.y, 0.f);
    o.z = fmaxf(v.z * sc[2] + sh[2] + hv.z, 0.f);
    o.w = fmaxf(v.w * sc[3] + sh[3] + hv.w, 0.f);
    *(float4*)(h + base) = o;
}

// ---------------- K7: gate = relu(h@W1+b1)@w2 + b2 ----------------
__global__ __launch_bounds__(256) void k_gate(
    const float* __restrict__ h, const float* __restrict__ w1,
    const float* __restrict__ b1, const float* __restrict__ w2,
    const float* __restrict__ b2, float* __restrict__ gate)
{
    __shared__ float As[64][33];
    __shared__ float Ws[32][132];
    int tid = threadIdx.x;
    int n0 = blockIdx.x * 64;
    int ct = tid & 15, rg = tid >> 4;
    int c0 = ct * 8;

    float acc[4][8];
    {
        float bias[8];
#pragma unroll
        for (int j = 0; j < 8; ++j) bias[j] = b1[c0 + j];
#pragma unroll
        for (int r = 0; r < 4; ++r)
#pragma unroll
            for (int j = 0; j < 8; ++j) acc[r][j] = bias[j];
    }

    const int lr = tid >> 2;
    const int lk = (tid & 3) * 8;
    const int wk = tid >> 3;
    const int wc = (tid & 7) * 16;

    for (int t = 0; t < 4; ++t) {
        int k0 = t * 32;
        const float4* ap = (const float4*)(h + (size_t)(n0 + lr) * H + k0 + lk);
        float4 a0 = ap[0], a1 = ap[1];
        const float4* wp = (const float4*)(w1 + (size_t)(k0 + wk) * H + wc);
        float4 w0 = wp[0], w1v = wp[1], w2v_ = wp[2], w3 = wp[3];
        __syncthreads();
        As[lr][lk + 0] = a0.x; As[lr][lk + 1] = a0.y; As[lr][lk + 2] = a0.z; As[lr][lk + 3] = a0.w;
        As[lr][lk + 4] = a1.x; As[lr][lk + 5] = a1.y; As[lr][lk + 6] = a1.z; As[lr][lk + 7] = a1.w;
        *(float4*)&Ws[wk][wc + 0]  = w0;
        *(float4*)&Ws[wk][wc + 4]  = w1v;
        *(float4*)&Ws[wk][wc + 8]  = w2v_;
        *(float4*)&Ws[wk][wc + 12] = w3;
        __syncthreads();
#pragma unroll
        for (int k = 0; k < 32; ++k) {
            float a0v = As[rg * 4 + 0][k];
            float a1v = As[rg * 4 + 1][k];
            float a2v = As[rg * 4 + 2][k];
            float a3v = As[rg * 4 + 3][k];
            float4 wv0 = *(const float4*)&Ws[k][c0];
            float4 wv1 = *(const float4*)&Ws[k][c0 + 4];
            acc[0][0] += a0v * wv0.x; acc[0][1] += a0v * wv0.y; acc[0][2] += a0v * wv0.z; acc[0][3] += a0v * wv0.w;
            acc[0][4] += a0v * wv1.x; acc[0][5] += a0v * wv1.y; acc[0][6] += a0v * wv1.z; acc[0][7] += a0v * wv1.w;
            acc[1][0] += a1v * wv0.x; acc[1][1] += a1v * wv0.y; acc[1][2] += a1v * wv0.z; acc[1][3] += a1v * wv0.w;
            acc[1][4] += a1v * wv1.x; acc[1][5] += a1v * wv1.y; acc[1][6] += a1v * wv1.z; acc[1][7] += a1v * wv1.w;
            acc[2][0] += a2v * wv0.x; acc[2][1] += a2v * wv0.y; acc[2][2] += a2v * wv0.z; acc[2][3] += a2v * wv0.w;
            acc[2][4] += a2v * wv1.x; acc[2][5] += a2v * wv1.y; acc[2][6] += a2v * wv1.z; acc[2][7] += a2v * wv1.w;
            acc[3][0] += a3v * wv0.x; acc[3][1] += a3v * wv0.y; acc[3][2] += a3v * wv0.z; acc[3][3] += a3v * wv0.w;
            acc[3][4] += a3v * wv1.x; acc[3][5] += a3v * wv1.y; acc[3][6] += a3v * wv1.z; acc[3][7] += a3v * wv1.w;
        }
    }

    // relu + dot with w2, reduce across 16 col-threads
    float w2loc[8];
#pragma unroll
    for (int j = 0; j < 8; ++j) w2loc[j] = w2[c0 + j];
    float gsum[4];
#pragma unroll
    for (int r = 0; r < 4; ++r) {
        float s = 0.f;
#pragma unroll
        for (int j = 0; j < 8; ++j) s += fmaxf(acc[r][j], 0.f) * w2loc[j];
        gsum[r] = s;
    }
    __syncthreads();
    float* Red = &As[0][0];   // need 16*64 floats
#pragma unroll
    for (int r = 0; r < 4; ++r) Red[ct * 64 + rg * 4 + r] = gsum[r];
    __syncthreads();
    if (tid < 64) {
        float s = 0.f;
#pragma unroll
        for (int t = 0; t < 16; ++t) s += Red[t * 64 + tid];
        gate[n0 + tid] = s + b2[0];
    }
}

// ---------------- K8: per-graph softmax over 64 contiguous nodes + weighted pool ----------------
__global__ __launch_bounds__(64) void k_pool(
    const float* __restrict__ gate, const float* __restrict__ h,
    float* __restrict__ pooled)
{
    int g = blockIdx.x, l = threadIdx.x;
    float gt = gate[g * SEG + l];
    float m = gt;
#pragma unroll
    for (int off = 32; off >= 1; off >>= 1) m = fmaxf(m, __shfl_xor(m, off));
    float e = expf(gt - m);
    float s = e;
#pragma unroll
    for (int off = 32; off >= 1; off >>= 1) s += __shfl_xor(s, off);
    float alpha = e / s;
    __shared__ float al[SEG];
    al[l] = alpha;
    __syncthreads();
    float p0 = 0.f, p1 = 0.f;
    const float* hb = h + (size_t)g * SEG * H;
    for (int j = 0; j < SEG; ++j) {
        float a = al[j];
        p0 += a * hb[(size_t)j * H + l];
        p1 += a * hb[(size_t)j * H + 64 + l];
    }
    pooled[(size_t)g * H + l] = p0;
    pooled[(size_t)g * H + 64 + l] = p1;
}

// ---------------- K9: global_embedding = [pooled, gf] @ gi_w + gi_b ----------------
__global__ __launch_bounds__(128) void k_final(
    const float* __restrict__ pooled, const float* __restrict__ gfeat,
    const float* __restrict__ gf_w, const float* __restrict__ gf_b,
    const float* __restrict__ gi_w, const float* __restrict__ gi_b,
    float* __restrict__ out)
{
    int g = blockIdx.x, c = threadIdx.x;
    __shared__ float prow[H], gfs[H];
    prow[c] = pooled[(size_t)g * H + c];
    float gv = gf_b[c];
    const float* gr = gfeat + (size_t)g * GF;
#pragma unroll
    for (int k = 0; k < GF; ++k) gv += gr[k] * gf_w[k * H + c];
    gfs[c] = gv;
    __syncthreads();
    float acc = gi_b[c];
    for (int k = 0; k < H; ++k) acc += prow[k] * gi_w[k * H + c];
    for (int k = 0; k < H; ++k) acc += gfs[k] * gi_w[(H + k) * H + c];
    out[(size_t)N_NODES * H + (size_t)g * H + c] = acc;
}

extern "C" void kernel_launch(void* const* d_in, const int* in_sizes, int n_in,
                              void* d_out, int out_size, void* d_ws, size_t ws_size,
                              hipStream_t stream)
{
    const float* x       = (const float*)d_in[0];
    const int*   ei      = (const int*)d_in[1];
    const float* eattr   = (const float*)d_in[2];
    const float* gfeat   = (const float*)d_in[3];
    // d_in[4] = batch (unused; batch[n] == n/64)
    const float* node_w  = (const float*)d_in[5];
    const float* node_b  = (const float*)d_in[6];
    const float* edge_w  = (const float*)d_in[7];
    const float* edge_b  = (const float*)d_in[8];
    const float* rel_w   = (const float*)d_in[9];
    const float* rel_b   = (const float*)d_in[10];
    const float* root_w  = (const float*)d_in[11];
    const float* bn_g    = (const float*)d_in[12];
    const float* bn_b    = (const float*)d_in[13];
    const float* gate_w1 = (const float*)d_in[14];
    const float* gate_b1 = (const float*)d_in[15];
    const float* gate_w2 = (const float*)d_in[16];
    const float* gate_b2 = (const float*)d_in[17];
    const float* gf_w    = (const float*)d_in[18];
    const float* gf_b    = (const float*)d_in[19];
    const float* gi_w    = (const float*)d_in[20];
    const float* gi_b    = (const float*)d_in[21];

    float* h      = (float*)d_out;                       // [N,H] output 0, live h
    float* out    = (float*)d_out;
    float* agg    = (float*)d_ws;                        // [N,H]; h2 aliases agg (safe, see K4)
    float* h2     = agg;
    float* stats  = agg + (size_t)N_NODES * H;           // 512 floats
    float* gate   = stats + 512;                         // [N]
    float* pooled = gate + N_NODES;                      // [G,H]
    int*   deg    = (int*)(pooled + (size_t)N_GRAPH * H);
    int*   rowptr = deg + N_NODES;                       // N+2 (pad for int2 align)
    int*   cursor = rowptr + N_NODES + 2;
    int*   bsum   = cursor + N_NODES;
    int*   boff   = bsum + NB_SCAN;
    int2*  pairs  = (int2*)(boff + NB_SCAN);             // [E] (src, edge_id)
    int*   rowtmp = cursor;                              // alias: rowtmp consumed before cursor written

    // ---- CSR build (once per launch) ----
    hipMemsetAsync(deg, 0, N_NODES * sizeof(int), stream);
    k_deg<<<(N_EDGES + 255) / 256, 256, 0, stream>>>(ei, deg);
    k_scan1<<<NB_SCAN, 256, 0, stream>>>(deg, rowtmp, bsum);
    k_scan2<<<1, 256, 0, stream>>>(bsum, boff);
    k_scan3<<<NB_SCAN, 256, 0, stream>>>(rowtmp, boff, rowptr, cursor);
    k_scatter<<<(N_EDGES + 255) / 256, 256, 0, stream>>>(ei, cursor, pairs);

    k_init_h<<<N_NODES * H / 256, 256, 0, stream>>>(x, node_w, node_b, h);
    hipMemsetAsync(stats, 0, 512 * sizeof(float), stream);

    for (int i = 0; i < LAYERS; ++i) {
        k_agg<<<N_NODES / 2, 256, 0, stream>>>(rowptr, pairs, eattr, edge_w, edge_b, h, agg);
        k_gemm_bn<<<N_NODES / 64, 256, 0, stream>>>(
            agg, h, rel_w + (size_t)i * H * H, root_w + (size_t)i * H * H,
            rel_b + (size_t)i * H, h2, stats);
        k_bn_stats<<<1, 128, 0, stream>>>(stats, bn_g + (size_t)i * H, bn_b + (size_t)i * H);
        k_bn_apply<<<N_NODES * H / 4 / 256, 256, 0, stream>>>(h2, stats, h);
    }

    k_gate<<<N_NODES / 64, 256, 0, stream>>>(h, gate_w1, gate_b1, gate_w2, gate_b2, gate);
    k_pool<<<N_GRAPH, SEG, 0, stream>>>(gate, h, pooled);
    k_final<<<N_GRAPH, H, 0, stream>>>(pooled, gfeat, gf_w, gf_b, gi_w, gi_b, out);
}

// Round 3
// 1645.946 us; speedup vs baseline: 1.9354x; 1.5992x over previous
//
#include <hip/hip_runtime.h>
#include <math.h>

#define N_NODES 204800
#define N_EDGES 600000
#define N_GRAPH 3200
#define H 128
#define NF 16
#define EF 5
#define GF 8
#define LAYERS 6
#define SEG 64
#define EPSV 1e-5f
#define NB_SCAN 800   // N_NODES / 256

typedef __attribute__((ext_vector_type(8))) short bf16x8;
typedef __attribute__((ext_vector_type(4))) float f32x4;

__device__ inline float bf2f(unsigned int u) {            // low 16 bits = bf16
    return __builtin_bit_cast(float, u << 16);
}
__device__ inline unsigned short f2bf(float f) {          // RNE
    unsigned int u = __builtin_bit_cast(unsigned int, f);
    u += 0x7fffu + ((u >> 16) & 1u);
    return (unsigned short)(u >> 16);
}

// ---------------- K1: h = x @ node_w + node_b (fp32 + bf16 copies) ----------------
__global__ __launch_bounds__(256) void k_init_h(
    const float* __restrict__ x, const float* __restrict__ node_w,
    const float* __restrict__ node_b, float* __restrict__ h,
    unsigned short* __restrict__ hb)
{
    int idx = blockIdx.x * 256 + threadIdx.x;   // n*32 + c4
    int n = idx >> 5, c0 = (idx & 31) * 4;
    float4 a = *(const float4*)(node_b + c0);
    const float* xr = x + n * NF;
#pragma unroll
    for (int k = 0; k < NF; ++k) {
        float xv = xr[k];
        float4 wv = *(const float4*)(node_w + k * H + c0);
        a.x += xv * wv.x; a.y += xv * wv.y; a.z += xv * wv.z; a.w += xv * wv.w;
    }
    *(float4*)(h + (size_t)n * H + c0) = a;
    unsigned int p0 = (unsigned int)f2bf(a.x) | ((unsigned int)f2bf(a.y) << 16);
    unsigned int p1 = (unsigned int)f2bf(a.z) | ((unsigned int)f2bf(a.w) << 16);
    *(uint2*)(hb + (size_t)n * H + c0) = make_uint2(p0, p1);
}

// ---------------- W repack: [rel|root] -> MFMA B-fragment order, bf16 ----------------
// wp[i][nb(8)][ks(8)][lane(64)][8]  ; ks 0..3 = rel (agg half), 4..7 = root (h half)
__global__ __launch_bounds__(64) void k_wpack(
    const float* __restrict__ relw, const float* __restrict__ rootw,
    unsigned short* __restrict__ wp)
{
    int bid = blockIdx.x;          // i*64 + nb*8 + ks
    int i = bid >> 6, f = bid & 63;
    int nb = f >> 3, ks = f & 7;
    int l = threadIdx.x;
    const float* src = (ks < 4) ? (relw + (size_t)i * H * H) : (rootw + (size_t)i * H * H);
    int ksl = ks & 3;
    int col = nb * 16 + (l & 15);
    int kbase = ksl * 32 + (l >> 4) * 8;
    unsigned short tmp[8];
#pragma unroll
    for (int m = 0; m < 8; ++m)
        tmp[m] = f2bf(src[(size_t)(kbase + m) * H + col]);
    *(uint4*)(wp + ((size_t)bid * 64 + l) * 8) = *(uint4*)tmp;
}

// ---------------- CSR build: deg -> scan -> scatter ----------------
__global__ __launch_bounds__(256) void k_deg(const int* __restrict__ ei, int* __restrict__ deg)
{
    int e = blockIdx.x * 256 + threadIdx.x;
    if (e < N_EDGES) atomicAdd(&deg[ei[N_EDGES + e]], 1);
}

__global__ __launch_bounds__(256) void k_scan1(
    const int* __restrict__ deg, int* __restrict__ rowtmp, int* __restrict__ bsum)
{
    __shared__ int sh[256];
    int t = threadIdx.x;
    int i = blockIdx.x * 256 + t;
    int v = deg[i];
    sh[t] = v;
    __syncthreads();
    for (int off = 1; off < 256; off <<= 1) {
        int a = (t >= off) ? sh[t - off] : 0;
        __syncthreads();
        sh[t] += a;
        __syncthreads();
    }
    rowtmp[i] = sh[t] - v;                 // exclusive
    if (t == 255) bsum[blockIdx.x] = sh[255];
}

__global__ void k_scan2(int* __restrict__ bsum, int* __restrict__ boff)  // 1 block x 256
{
    __shared__ int sh[256];
    __shared__ int carry;
    int t = threadIdx.x;
    if (t == 0) carry = 0;
    __syncthreads();
    for (int base = 0; base < NB_SCAN; base += 256) {
        int i = base + t;
        int v = (i < NB_SCAN) ? bsum[i] : 0;
        sh[t] = v;
        __syncthreads();
        for (int off = 1; off < 256; off <<= 1) {
            int a = (t >= off) ? sh[t - off] : 0;
            __syncthreads();
            sh[t] += a;
            __syncthreads();
        }
        if (i < NB_SCAN) boff[i] = carry + sh[t] - v;
        __syncthreads();
        if (t == 0) carry += sh[255];
        __syncthreads();
    }
}

__global__ __launch_bounds__(256) void k_scan3(
    const int* __restrict__ rowtmp, const int* __restrict__ boff,
    int* __restrict__ rowptr, int* __restrict__ cursor)
{
    int i = blockIdx.x * 256 + threadIdx.x;
    int r = rowtmp[i] + boff[blockIdx.x];
    rowptr[i] = r;
    cursor[i] = r;
    if (i == 0) rowptr[N_NODES] = N_EDGES;
}

__global__ __launch_bounds__(256) void k_scatter(
    const int* __restrict__ ei, int* __restrict__ cursor, int2* __restrict__ pairs)
{
    int e = blockIdx.x * 256 + threadIdx.x;
    if (e >= N_EDGES) return;
    int d = ei[N_EDGES + e];
    int pos = atomicAdd(&cursor[d], 1);
    pairs[pos] = make_int2(ei[e], e);      // (src, edge_id)
}

// ---------------- K3: pull-mode aggregation, bf16 in/out, 1 wave per node ----------------
__global__ __launch_bounds__(256) void k_agg(
    const int* __restrict__ rowptr, const int2* __restrict__ pairs,
    const float* __restrict__ eattr,
    const float* __restrict__ edge_w, const float* __restrict__ edge_b,
    const unsigned short* __restrict__ hb, unsigned short* __restrict__ aggb)
{
    int w = threadIdx.x >> 6, l = threadIdx.x & 63;
    int n = blockIdx.x * 4 + w;
    float2 ew2[EF];
#pragma unroll
    for (int k = 0; k < EF; ++k) ew2[k] = ((const float2*)(edge_w + k * H))[l];
    float2 eb2 = ((const float2*)edge_b)[l];
    float a0 = 0.f, a1 = 0.f;
    int j = rowptr[n], j1 = rowptr[n + 1];
    for (; j + 2 <= j1; j += 2) {
        int2 pa = pairs[j], pb = pairs[j + 1];
        const float* ara = eattr + (size_t)pa.y * EF;
        const float* arb = eattr + (size_t)pb.y * EF;
        unsigned int hva = *(const unsigned int*)(hb + (size_t)pa.x * H + 2 * l);
        unsigned int hvb = *(const unsigned int*)(hb + (size_t)pb.x * H + 2 * l);
        float ea0 = eb2.x, ea1 = eb2.y, fb0 = eb2.x, fb1 = eb2.y;
#pragma unroll
        for (int k = 0; k < EF; ++k) {
            float va = ara[k], vb = arb[k];
            ea0 += va * ew2[k].x; ea1 += va * ew2[k].y;
            fb0 += vb * ew2[k].x; fb1 += vb * ew2[k].y;
        }
        a0 += bf2f(hva & 0xffffu) * ea0 + bf2f(hvb & 0xffffu) * fb0;
        a1 += bf2f(hva >> 16) * ea1 + bf2f(hvb >> 16) * fb1;
    }
    if (j < j1) {
        int2 pa = pairs[j];
        const float* ara = eattr + (size_t)pa.y * EF;
        unsigned int hva = *(const unsigned int*)(hb + (size_t)pa.x * H + 2 * l);
        float ea0 = eb2.x, ea1 = eb2.y;
#pragma unroll
        for (int k = 0; k < EF; ++k) {
            float va = ara[k];
            ea0 += va * ew2[k].x; ea1 += va * ew2[k].y;
        }
        a0 += bf2f(hva & 0xffffu) * ea0;
        a1 += bf2f(hva >> 16) * ea1;
    }
    unsigned int pk = (unsigned int)f2bf(a0) | ((unsigned int)f2bf(a1) << 16);
    *(unsigned int*)(aggb + (size_t)n * H + 2 * l) = pk;
}

// ---------------- K4: MFMA dual-GEMM + BN col sums; h2 (bf16) written in-place over aggb ----
// block = 256 (4 waves); tile 64 rows x 128 cols; wave w: all 64 rows x cols [w*32, w*32+32)
__global__ __launch_bounds__(256) void k_gemm_mfma(
    const unsigned short* __restrict__ aggb,
    const unsigned short* __restrict__ hb,
    const unsigned short* __restrict__ wp,      // this layer's 64KB packed [rel|root]
    const float* __restrict__ relb,
    unsigned short* __restrict__ h2b,           // == aggb (in-place; barrier protects)
    float* __restrict__ stats)
{
    int tid = threadIdx.x;
    int w = tid >> 6, l = tid & 63;
    int n0 = blockIdx.x * 64;
    int lr = l & 15, hi = l >> 4;

    f32x4 acc[4][2];
#pragma unroll
    for (int rb = 0; rb < 4; ++rb) {
        acc[rb][0] = (f32x4){0.f, 0.f, 0.f, 0.f};
        acc[rb][1] = (f32x4){0.f, 0.f, 0.f, 0.f};
    }

    const bf16x8* wv = (const bf16x8*)wp;
#pragma unroll
    for (int ks = 0; ks < 4; ++ks) {
        bf16x8 b0 = wv[((2 * w + 0) * 8 + ks) * 64 + l];
        bf16x8 b1 = wv[((2 * w + 1) * 8 + ks) * 64 + l];
#pragma unroll
        for (int rb = 0; rb < 4; ++rb) {
            bf16x8 a = *(const bf16x8*)(aggb + (size_t)(n0 + rb * 16 + lr) * H + ks * 32 + hi * 8);
            acc[rb][0] = __builtin_amdgcn_mfma_f32_16x16x32_bf16(a, b0, acc[rb][0], 0, 0, 0);
            acc[rb][1] = __builtin_amdgcn_mfma_f32_16x16x32_bf16(a, b1, acc[rb][1], 0, 0, 0);
        }
    }
#pragma unroll
    for (int ks = 0; ks < 4; ++ks) {
        bf16x8 b0 = wv[((2 * w + 0) * 8 + 4 + ks) * 64 + l];
        bf16x8 b1 = wv[((2 * w + 1) * 8 + 4 + ks) * 64 + l];
#pragma unroll
        for (int rb = 0; rb < 4; ++rb) {
            bf16x8 a = *(const bf16x8*)(hb + (size_t)(n0 + rb * 16 + lr) * H + ks * 32 + hi * 8);
            acc[rb][0] = __builtin_amdgcn_mfma_f32_16x16x32_bf16(a, b0, acc[rb][0], 0, 0, 0);
            acc[rb][1] = __builtin_amdgcn_mfma_f32_16x16x32_bf16(a, b1, acc[rb][1], 0, 0, 0);
        }
    }

    // all waves' reads of aggb rows [n0,n0+64) must complete before in-place stores
    __syncthreads();

#pragma unroll
    for (int nbl = 0; nbl < 2; ++nbl) {
        int col = w * 32 + nbl * 16 + lr;
        float bs = relb[col];
        float csum = 0.f, csq = 0.f;
#pragma unroll
        for (int rb = 0; rb < 4; ++rb) {
#pragma unroll
            for (int jj = 0; jj < 4; ++jj) {
                float v = acc[rb][nbl][jj] + bs;
                h2b[(size_t)(n0 + rb * 16 + hi * 4 + jj) * H + col] = f2bf(v);
                csum += v; csq += v * v;
            }
        }
        csum += __shfl_xor(csum, 16); csum += __shfl_xor(csum, 32);
        csq  += __shfl_xor(csq, 16);  csq  += __shfl_xor(csq, 32);
        if (hi == 0) {
            atomicAdd(&stats[col], csum);
            atomicAdd(&stats[H + col], csq);
        }
    }
}

// ---------------- K5: BN stats -> scale/shift, rezero accumulators ----------------
__global__ void k_bn_stats(float* stats, const float* __restrict__ gamma,
                           const float* __restrict__ beta)
{
    int c = threadIdx.x;
    float s = stats[c], sq = stats[H + c];
    float mean = s / (float)N_NODES;
    float var = sq / (float)N_NODES - mean * mean;
    var = fmaxf(var, 0.f);
    float scale = gamma[c] * rsqrtf(var + EPSV);
    float shift = beta[c] - mean * scale;
    stats[2 * H + c] = scale;
    stats[3 * H + c] = shift;
    stats[c] = 0.f;
    stats[H + c] = 0.f;
}

// ---------------- K6: h = relu(h2*scale + shift + h); also write h_bf16 ----------------
__global__ __launch_bounds__(256) void k_bn_apply(
    const unsigned short* __restrict__ h2b, const float* __restrict__ stats,
    float* __restrict__ h, unsigned short* __restrict__ hb)
{
    size_t base = ((size_t)blockIdx.x * 256 + threadIdx.x) * 8;
    int c = (int)(base & 127);
    uint4 hv2 = *(const uint4*)(h2b + base);
    float4 h0 = *(const float4*)(h + base);
    float4 h1 = *(const float4*)(h + base + 4);
    const float* sc = stats + 2 * H + c;
    const float* sh = stats + 3 * H + c;
    float o[8];
    unsigned int u[4] = {hv2.x, hv2.y, hv2.z, hv2.w};
    float hv[8] = {h0.x, h0.y, h0.z, h0.w, h1.x, h1.y, h1.z, h1.w};
#pragma unroll
    for (int k = 0; k < 4; ++k) {
        float vlo = bf2f(u[k] & 0xffffu);
        float vhi = bf2f(u[k] >> 16);
        o[2 * k]     = fmaxf(vlo * sc[2 * k]     + sh[2 * k]     + hv[2 * k], 0.f);
        o[2 * k + 1] = fmaxf(vhi * sc[2 * k + 1] + sh[2 * k + 1] + hv[2 * k + 1], 0.f);
    }
    *(float4*)(h + base)     = make_float4(o[0], o[1], o[2], o[3]);
    *(float4*)(h + base + 4) = make_float4(o[4], o[5], o[6], o[7]);
    uint4 pk;
    pk.x = (unsigned int)f2bf(o[0]) | ((unsigned int)f2bf(o[1]) << 16);
    pk.y = (unsigned int)f2bf(o[2]) | ((unsigned int)f2bf(o[3]) << 16);
    pk.z = (unsigned int)f2bf(o[4]) | ((unsigned int)f2bf(o[5]) << 16);
    pk.w = (unsigned int)f2bf(o[6]) | ((unsigned int)f2bf(o[7]) << 16);
    *(uint4*)(hb + base) = pk;
}

// ---------------- K7: gate = relu(h@W1+b1)@w2 + b2 (fp32, runs once) ----------------
__global__ __launch_bounds__(256) void k_gate(
    const float* __restrict__ h, const float* __restrict__ w1,
    const float* __restrict__ b1, const float* __restrict__ w2,
    const float* __restrict__ b2, float* __restrict__ gate)
{
    __shared__ float As[64][33];
    __shared__ float Ws[32][132];
    int tid = threadIdx.x;
    int n0 = blockIdx.x * 64;
    int ct = tid & 15, rg = tid >> 4;
    int c0 = ct * 8;

    float acc[4][8];
    {
        float bias[8];
#pragma unroll
        for (int j = 0; j < 8; ++j) bias[j] = b1[c0 + j];
#pragma unroll
        for (int r = 0; r < 4; ++r)
#pragma unroll
            for (int j = 0; j < 8; ++j) acc[r][j] = bias[j];
    }

    const int lr = tid >> 2;
    const int lk = (tid & 3) * 8;
    const int wk = tid >> 3;
    const int wc = (tid & 7) * 16;

    for (int t = 0; t < 4; ++t) {
        int k0 = t * 32;
        const float4* ap = (const float4*)(h + (size_t)(n0 + lr) * H + k0 + lk);
        float4 a0 = ap[0], a1 = ap[1];
        const float4* wpp = (const float4*)(w1 + (size_t)(k0 + wk) * H + wc);
        float4 w0 = wpp[0], w1v = wpp[1], w2v_ = wpp[2], w3 = wpp[3];
        __syncthreads();
        As[lr][lk + 0] = a0.x; As[lr][lk + 1] = a0.y; As[lr][lk + 2] = a0.z; As[lr][lk + 3] = a0.w;
        As[lr][lk + 4] = a1.x; As[lr][lk + 5] = a1.y; As[lr][lk + 6] = a1.z; As[lr][lk + 7] = a1.w;
        *(float4*)&Ws[wk][wc + 0]  = w0;
        *(float4*)&Ws[wk][wc + 4]  = w1v;
        *(float4*)&Ws[wk][wc + 8]  = w2v_;
        *(float4*)&Ws[wk][wc + 12] = w3;
        __syncthreads();
#pragma unroll
        for (int k = 0; k < 32; ++k) {
            float a0v = As[rg * 4 + 0][k];
            float a1v = As[rg * 4 + 1][k];
            float a2v = As[rg * 4 + 2][k];
            float a3v = As[rg * 4 + 3][k];
            float4 wv0 = *(const float4*)&Ws[k][c0];
            float4 wv1 = *(const float4*)&Ws[k][c0 + 4];
            acc[0][0] += a0v * wv0.x; acc[0][1] += a0v * wv0.y; acc[0][2] += a0v * wv0.z; acc[0][3] += a0v * wv0.w;
            acc[0][4] += a0v * wv1.x; acc[0][5] += a0v * wv1.y; acc[0][6] += a0v * wv1.z; acc[0][7] += a0v * wv1.w;
            acc[1][0] += a1v * wv0.x; acc[1][1] += a1v * wv0.y; acc[1][2] += a1v * wv0.z; acc[1][3] += a1v * wv0.w;
            acc[1][4] += a1v * wv1.x; acc[1][5] += a1v * wv1.y; acc[1][6] += a1v * wv1.z; acc[1][7] += a1v * wv1.w;
            acc[2][0] += a2v * wv0.x; acc[2][1] += a2v * wv0.y; acc[2][2] += a2v * wv0.z; acc[2][3] += a2v * wv0.w;
            acc[2][4] += a2v * wv1.x; acc[2][5] += a2v * wv1.y; acc[2][6] += a2v * wv1.z; acc[2][7] += a2v * wv1.w;
            acc[3][0] += a3v * wv0.x; acc[3][1] += a3v * wv0.y; acc[3][2] += a3v * wv0.z; acc[3][3] += a3v * wv0.w;
            acc[3][4] += a3v * wv1.x; acc[3][5] += a3v * wv1.y; acc[3][6] += a3v * wv1.z; acc[3][7] += a3v * wv1.w;
        }
    }

    float w2loc[8];
#pragma unroll
    for (int j = 0; j < 8; ++j) w2loc[j] = w2[c0 + j];
    float gsum[4];
#pragma unroll
    for (int r = 0; r < 4; ++r) {
        float s = 0.f;
#pragma unroll
        for (int j = 0; j < 8; ++j) s += fmaxf(acc[r][j], 0.f) * w2loc[j];
        gsum[r] = s;
    }
    __syncthreads();
    float* Red = &As[0][0];
#pragma unroll
    for (int r = 0; r < 4; ++r) Red[ct * 64 + rg * 4 + r] = gsum[r];
    __syncthreads();
    if (tid < 64) {
        float s = 0.f;
#pragma unroll
        for (int t = 0; t < 16; ++t) s += Red[t * 64 + tid];
        gate[n0 + tid] = s + b2[0];
    }
}

// ---------------- K8: per-graph softmax over 64 contiguous nodes + weighted pool ----------
__global__ __launch_bounds__(64) void k_pool(
    const float* __restrict__ gate, const float* __restrict__ h,
    float* __restrict__ pooled)
{
    int g = blockIdx.x, l = threadIdx.x;
    float gt = gate[g * SEG + l];
    float m = gt;
#pragma unroll
    for (int off = 32; off >= 1; off >>= 1) m = fmaxf(m, __shfl_xor(m, off));
    float e = expf(gt - m);
    float s = e;
#pragma unroll
    for (int off = 32; off >= 1; off >>= 1) s += __shfl_xor(s, off);
    float alpha = e / s;
    __shared__ float al[SEG];
    al[l] = alpha;
    __syncthreads();
    float p0 = 0.f, p1 = 0.f;
    const float* hbp = h + (size_t)g * SEG * H;
    for (int j = 0; j < SEG; ++j) {
        float a = al[j];
        p0 += a * hbp[(size_t)j * H + l];
        p1 += a * hbp[(size_t)j * H + 64 + l];
    }
    pooled[(size_t)g * H + l] = p0;
    pooled[(size_t)g * H + 64 + l] = p1;
}

// ---------------- K9: global_embedding = [pooled, gf] @ gi_w + gi_b ----------------
__global__ __launch_bounds__(128) void k_final(
    const float* __restrict__ pooled, const float* __restrict__ gfeat,
    const float* __restrict__ gf_w, const float* __restrict__ gf_b,
    const float* __restrict__ gi_w, const float* __restrict__ gi_b,
    float* __restrict__ out)
{
    int g = blockIdx.x, c = threadIdx.x;
    __shared__ float prow[H], gfs[H];
    prow[c] = pooled[(size_t)g * H + c];
    float gv = gf_b[c];
    const float* gr = gfeat + (size_t)g * GF;
#pragma unroll
    for (int k = 0; k < GF; ++k) gv += gr[k] * gf_w[k * H + c];
    gfs[c] = gv;
    __syncthreads();
    float acc = gi_b[c];
    for (int k = 0; k < H; ++k) acc += prow[k] * gi_w[k * H + c];
    for (int k = 0; k < H; ++k) acc += gfs[k] * gi_w[(H + k) * H + c];
    out[(size_t)N_NODES * H + (size_t)g * H + c] = acc;
}

extern "C" void kernel_launch(void* const* d_in, const int* in_sizes, int n_in,
                              void* d_out, int out_size, void* d_ws, size_t ws_size,
                              hipStream_t stream)
{
    const float* x       = (const float*)d_in[0];
    const int*   ei      = (const int*)d_in[1];
    const float* eattr   = (const float*)d_in[2];
    const float* gfeat   = (const float*)d_in[3];
    // d_in[4] = batch (unused; batch[n] == n/64)
    const float* node_w  = (const float*)d_in[5];
    const float* node_b  = (const float*)d_in[6];
    const float* edge_w  = (const float*)d_in[7];
    const float* edge_b  = (const float*)d_in[8];
    const float* rel_w   = (const float*)d_in[9];
    const float* rel_b   = (const float*)d_in[10];
    const float* root_w  = (const float*)d_in[11];
    const float* bn_g    = (const float*)d_in[12];
    const float* bn_b    = (const float*)d_in[13];
    const float* gate_w1 = (const float*)d_in[14];
    const float* gate_b1 = (const float*)d_in[15];
    const float* gate_w2 = (const float*)d_in[16];
    const float* gate_b2 = (const float*)d_in[17];
    const float* gf_w    = (const float*)d_in[18];
    const float* gf_b    = (const float*)d_in[19];
    const float* gi_w    = (const float*)d_in[20];
    const float* gi_b    = (const float*)d_in[21];

    float* h   = (float*)d_out;                          // [N,H] output 0
    float* out = (float*)d_out;

    unsigned short* aggb = (unsigned short*)d_ws;        // [N,H] bf16; h2b aliases (in-place)
    unsigned short* hb   = aggb + (size_t)N_NODES * H;   // [N,H] bf16 copy of h
    unsigned short* wpck = hb + (size_t)N_NODES * H;     // [L][8][8][64][8] bf16 = 384KB
    float* stats  = (float*)(wpck + (size_t)LAYERS * 32768);
    float* gate   = stats + 512;
    float* pooled = gate + N_NODES;
    int*   deg    = (int*)(pooled + (size_t)N_GRAPH * H);
    int*   rowptr = deg + N_NODES;                       // N+4
    int*   cursor = rowptr + N_NODES + 4;
    int*   bsum   = cursor + N_NODES;
    int*   boff   = bsum + NB_SCAN;
    int2*  pairs  = (int2*)(boff + NB_SCAN);             // [E] (src, edge_id)
    int*   rowtmp = cursor;                              // alias ok (k_scan3 reads then writes same idx)

    // ---- CSR build + weight repack (once per launch) ----
    hipMemsetAsync(deg, 0, N_NODES * sizeof(int), stream);
    k_deg<<<(N_EDGES + 255) / 256, 256, 0, stream>>>(ei, deg);
    k_scan1<<<NB_SCAN, 256, 0, stream>>>(deg, rowtmp, bsum);
    k_scan2<<<1, 256, 0, stream>>>(bsum, boff);
    k_scan3<<<NB_SCAN, 256, 0, stream>>>(rowtmp, boff, rowptr, cursor);
    k_scatter<<<(N_EDGES + 255) / 256, 256, 0, stream>>>(ei, cursor, pairs);
    k_wpack<<<LAYERS * 64, 64, 0, stream>>>(rel_w, root_w, wpck);

    k_init_h<<<N_NODES * 32 / 256, 256, 0, stream>>>(x, node_w, node_b, h, hb);
    hipMemsetAsync(stats, 0, 512 * sizeof(float), stream);

    for (int i = 0; i < LAYERS; ++i) {
        k_agg<<<N_NODES / 4, 256, 0, stream>>>(rowptr, pairs, eattr, edge_w, edge_b, hb, aggb);
        k_gemm_mfma<<<N_NODES / 64, 256, 0, stream>>>(
            aggb, hb, wpck + (size_t)i * 32768, rel_b + (size_t)i * H, aggb, stats);
        k_bn_stats<<<1, 128, 0, stream>>>(stats, bn_g + (size_t)i * H, bn_b + (size_t)i * H);
        k_bn_apply<<<N_NODES * H / 8 / 256, 256, 0, stream>>>(aggb, stats, h, hb);
    }

    k_gate<<<N_NODES / 64, 256, 0, stream>>>(h, gate_w1, gate_b1, gate_w2, gate_b2, gate);
    k_pool<<<N_GRAPH, SEG, 0, stream>>>(gate, h, pooled);
    k_final<<<N_GRAPH, H, 0, stream>>>(pooled, gfeat, gf_w, gf_b, gi_w, gi_b, out);
}

// Round 4
// 1429.808 us; speedup vs baseline: 2.2280x; 1.1512x over previous
//
#include <hip/hip_runtime.h>
#include <math.h>

#define N_NODES 204800
#define N_EDGES 600000
#define N_GRAPH 3200
#define H 128
#define NF 16
#define EF 5
#define GF 8
#define LAYERS 6
#define SEG 64
#define EPSV 1e-5f
#define NB_SCAN 800   // N_NODES / 256

typedef __attribute__((ext_vector_type(8))) short bf16x8;
typedef __attribute__((ext_vector_type(4))) float f32x4;

__device__ inline float bf2f(unsigned int u) {            // low 16 bits = bf16
    return __builtin_bit_cast(float, u << 16);
}
__device__ inline unsigned short f2bf(float f) {          // RNE
    unsigned int u = __builtin_bit_cast(unsigned int, f);
    u += 0x7fffu + ((u >> 16) & 1u);
    return (unsigned short)(u >> 16);
}

// ---------------- K1: hb = bf16(x @ node_w + node_b) ----------------
__global__ __launch_bounds__(256) void k_init_h(
    const float* __restrict__ x, const float* __restrict__ node_w,
    const float* __restrict__ node_b, unsigned short* __restrict__ hb)
{
    int idx = blockIdx.x * 256 + threadIdx.x;   // n*32 + c4
    int n = idx >> 5, c0 = (idx & 31) * 4;
    float4 a = *(const float4*)(node_b + c0);
    const float* xr = x + n * NF;
#pragma unroll
    for (int k = 0; k < NF; ++k) {
        float xv = xr[k];
        float4 wv = *(const float4*)(node_w + k * H + c0);
        a.x += xv * wv.x; a.y += xv * wv.y; a.z += xv * wv.z; a.w += xv * wv.w;
    }
    unsigned int p0 = (unsigned int)f2bf(a.x) | ((unsigned int)f2bf(a.y) << 16);
    unsigned int p1 = (unsigned int)f2bf(a.z) | ((unsigned int)f2bf(a.w) << 16);
    *(uint2*)(hb + (size_t)n * H + c0) = make_uint2(p0, p1);
}

// ---------------- W repack: [rel|root] -> MFMA B-fragment order, bf16 ----------------
// wp[i][nb(8)][ks(8)][lane(64)][8]  ; ks 0..3 = rel (agg half), 4..7 = root (h half)
__global__ __launch_bounds__(64) void k_wpack(
    const float* __restrict__ relw, const float* __restrict__ rootw,
    unsigned short* __restrict__ wp)
{
    int bid = blockIdx.x;          // i*64 + nb*8 + ks
    int i = bid >> 6, f = bid & 63;
    int nb = f >> 3, ks = f & 7;
    int l = threadIdx.x;
    const float* src = (ks < 4) ? (relw + (size_t)i * H * H) : (rootw + (size_t)i * H * H);
    int ksl = ks & 3;
    int col = nb * 16 + (l & 15);
    int kbase = ksl * 32 + (l >> 4) * 8;
    unsigned short tmp[8];
#pragma unroll
    for (int m = 0; m < 8; ++m)
        tmp[m] = f2bf(src[(size_t)(kbase + m) * H + col]);
    *(uint4*)(wp + ((size_t)bid * 64 + l) * 8) = *(uint4*)tmp;
}

// gate_w1 pack: gwp[nb(8)][ks(4)][lane(64)][8]
__global__ __launch_bounds__(64) void k_wpack_gate(
    const float* __restrict__ gw1, unsigned short* __restrict__ gwp)
{
    int bid = blockIdx.x;          // nb*4 + ks
    int nb = bid >> 2, ks = bid & 3;
    int l = threadIdx.x;
    int col = nb * 16 + (l & 15);
    int kbase = ks * 32 + (l >> 4) * 8;
    unsigned short tmp[8];
#pragma unroll
    for (int m = 0; m < 8; ++m)
        tmp[m] = f2bf(gw1[(size_t)(kbase + m) * H + col]);
    *(uint4*)(gwp + ((size_t)bid * 64 + l) * 8) = *(uint4*)tmp;
}

// ---------------- CSR build: deg -> scan -> scatter ----------------
__global__ __launch_bounds__(256) void k_deg(const int* __restrict__ ei, int* __restrict__ deg)
{
    int e = blockIdx.x * 256 + threadIdx.x;
    if (e < N_EDGES) atomicAdd(&deg[ei[N_EDGES + e]], 1);
}

__global__ __launch_bounds__(256) void k_scan1(
    const int* __restrict__ deg, int* __restrict__ rowtmp, int* __restrict__ bsum)
{
    __shared__ int sh[256];
    int t = threadIdx.x;
    int i = blockIdx.x * 256 + t;
    int v = deg[i];
    sh[t] = v;
    __syncthreads();
    for (int off = 1; off < 256; off <<= 1) {
        int a = (t >= off) ? sh[t - off] : 0;
        __syncthreads();
        sh[t] += a;
        __syncthreads();
    }
    rowtmp[i] = sh[t] - v;                 // exclusive
    if (t == 255) bsum[blockIdx.x] = sh[255];
}

__global__ void k_scan2(int* __restrict__ bsum, int* __restrict__ boff)  // 1 block x 256
{
    __shared__ int sh[256];
    __shared__ int carry;
    int t = threadIdx.x;
    if (t == 0) carry = 0;
    __syncthreads();
    for (int base = 0; base < NB_SCAN; base += 256) {
        int i = base + t;
        int v = (i < NB_SCAN) ? bsum[i] : 0;
        sh[t] = v;
        __syncthreads();
        for (int off = 1; off < 256; off <<= 1) {
            int a = (t >= off) ? sh[t - off] : 0;
            __syncthreads();
            sh[t] += a;
            __syncthreads();
        }
        if (i < NB_SCAN) boff[i] = carry + sh[t] - v;
        __syncthreads();
        if (t == 0) carry += sh[255];
        __syncthreads();
    }
}

__global__ __launch_bounds__(256) void k_scan3(
    const int* __restrict__ rowtmp, const int* __restrict__ boff,
    int* __restrict__ rowptr, int* __restrict__ cursor)
{
    int i = blockIdx.x * 256 + threadIdx.x;
    int r = rowtmp[i] + boff[blockIdx.x];
    rowptr[i] = r;
    cursor[i] = r;
    if (i == 0) rowptr[N_NODES] = N_EDGES;
}

__global__ __launch_bounds__(256) void k_scatter(
    const int* __restrict__ ei, int* __restrict__ cursor, int2* __restrict__ pairs)
{
    int e = blockIdx.x * 256 + threadIdx.x;
    if (e >= N_EDGES) return;
    int d = ei[N_EDGES + e];
    int pos = atomicAdd(&cursor[d], 1);
    pairs[pos] = make_int2(ei[e], e);      // (src, edge_id)
}

// ---------------- K_LAYER: fused gather-agg (LDS) + dual MFMA + BN col sums -------------
// block = 256 (4 waves), 64 nodes. Phase 1: wave w stages agg rows [w*16, w*16+16) into
// swizzled LDS (bf16). Phase 2: h2 = agg@rel + h@root + bias -> h2b; col sum/sumsq atomics.
__global__ __launch_bounds__(256) void k_layer(
    const int* __restrict__ rowptr, const int2* __restrict__ pairs,
    const float* __restrict__ eattr,
    const float* __restrict__ edge_w, const float* __restrict__ edge_b,
    const unsigned short* __restrict__ hb,
    const unsigned short* __restrict__ wp,      // this layer's packed [rel|root]
    const float* __restrict__ relb,
    unsigned short* __restrict__ h2b,
    float* __restrict__ stats)                  // this layer's [256] (sum, sumsq)
{
    __shared__ unsigned int sm[64 * 64];        // [row][64 dwords], dw ^= (row&7)*4 swizzle
    int tid = threadIdx.x;
    int w = tid >> 6, l = tid & 63;
    int n0 = blockIdx.x * 64;

    // ---- phase 1: gather-aggregate 16 nodes per wave ----
    float2 ew2[EF];
#pragma unroll
    for (int k = 0; k < EF; ++k) ew2[k] = ((const float2*)(edge_w + k * H))[l];
    float2 eb2 = ((const float2*)edge_b)[l];

    for (int i = 0; i < 16; ++i) {
        int r = w * 16 + i;
        int n = n0 + r;
        float a0 = 0.f, a1 = 0.f;
        int j = rowptr[n], j1 = rowptr[n + 1];
        for (; j + 2 <= j1; j += 2) {
            int2 pa = pairs[j], pb = pairs[j + 1];
            const float* ara = eattr + (size_t)pa.y * EF;
            const float* arb = eattr + (size_t)pb.y * EF;
            unsigned int hva = *(const unsigned int*)(hb + (size_t)pa.x * H + 2 * l);
            unsigned int hvb = *(const unsigned int*)(hb + (size_t)pb.x * H + 2 * l);
            float ea0 = eb2.x, ea1 = eb2.y, fb0 = eb2.x, fb1 = eb2.y;
#pragma unroll
            for (int k = 0; k < EF; ++k) {
                float va = ara[k], vb = arb[k];
                ea0 += va * ew2[k].x; ea1 += va * ew2[k].y;
                fb0 += vb * ew2[k].x; fb1 += vb * ew2[k].y;
            }
            a0 += bf2f(hva & 0xffffu) * ea0 + bf2f(hvb & 0xffffu) * fb0;
            a1 += bf2f(hva >> 16) * ea1 + bf2f(hvb >> 16) * fb1;
        }
        if (j < j1) {
            int2 pa = pairs[j];
            const float* ara = eattr + (size_t)pa.y * EF;
            unsigned int hva = *(const unsigned int*)(hb + (size_t)pa.x * H + 2 * l);
            float ea0 = eb2.x, ea1 = eb2.y;
#pragma unroll
            for (int k = 0; k < EF; ++k) {
                float va = ara[k];
                ea0 += va * ew2[k].x; ea1 += va * ew2[k].y;
            }
            a0 += bf2f(hva & 0xffffu) * ea0;
            a1 += bf2f(hva >> 16) * ea1;
        }
        unsigned int pk = (unsigned int)f2bf(a0) | ((unsigned int)f2bf(a1) << 16);
        sm[r * 64 + (l ^ ((r & 7) * 4))] = pk;
    }
    __syncthreads();

    // ---- phase 2: dual MFMA ----
    int lr = l & 15, hi = l >> 4;
    f32x4 acc[4][2];
#pragma unroll
    for (int rb = 0; rb < 4; ++rb) {
        acc[rb][0] = (f32x4){0.f, 0.f, 0.f, 0.f};
        acc[rb][1] = (f32x4){0.f, 0.f, 0.f, 0.f};
    }
    const bf16x8* wv = (const bf16x8*)wp;
#pragma unroll
    for (int ks = 0; ks < 4; ++ks) {           // agg half: A from LDS
        bf16x8 b0 = wv[((2 * w + 0) * 8 + ks) * 64 + l];
        bf16x8 b1 = wv[((2 * w + 1) * 8 + ks) * 64 + l];
#pragma unroll
        for (int rb = 0; rb < 4; ++rb) {
            int rr = rb * 16 + lr;
            int dc = ks * 16 + hi * 4;
            bf16x8 a = *(const bf16x8*)&sm[rr * 64 + (dc ^ ((rr & 7) * 4))];
            acc[rb][0] = __builtin_amdgcn_mfma_f32_16x16x32_bf16(a, b0, acc[rb][0], 0, 0, 0);
            acc[rb][1] = __builtin_amdgcn_mfma_f32_16x16x32_bf16(a, b1, acc[rb][1], 0, 0, 0);
        }
    }
#pragma unroll
    for (int ks = 0; ks < 4; ++ks) {           // root half: A from global hb
        bf16x8 b0 = wv[((2 * w + 0) * 8 + 4 + ks) * 64 + l];
        bf16x8 b1 = wv[((2 * w + 1) * 8 + 4 + ks) * 64 + l];
#pragma unroll
        for (int rb = 0; rb < 4; ++rb) {
            bf16x8 a = *(const bf16x8*)(hb + (size_t)(n0 + rb * 16 + lr) * H + ks * 32 + hi * 8);
            acc[rb][0] = __builtin_amdgcn_mfma_f32_16x16x32_bf16(a, b0, acc[rb][0], 0, 0, 0);
            acc[rb][1] = __builtin_amdgcn_mfma_f32_16x16x32_bf16(a, b1, acc[rb][1], 0, 0, 0);
        }
    }

    // ---- epilogue: bias, bf16 store, BN col sums ----
#pragma unroll
    for (int nbl = 0; nbl < 2; ++nbl) {
        int col = w * 32 + nbl * 16 + lr;
        float bs = relb[col];
        float csum = 0.f, csq = 0.f;
#pragma unroll
        for (int rb = 0; rb < 4; ++rb) {
#pragma unroll
            for (int jj = 0; jj < 4; ++jj) {
                float v = acc[rb][nbl][jj] + bs;
                h2b[(size_t)(n0 + rb * 16 + hi * 4 + jj) * H + col] = f2bf(v);
                csum += v; csq += v * v;
            }
        }
        csum += __shfl_xor(csum, 16); csum += __shfl_xor(csum, 32);
        csq  += __shfl_xor(csq, 16);  csq  += __shfl_xor(csq, 32);
        if (hi == 0) {
            atomicAdd(&stats[col], csum);
            atomicAdd(&stats[H + col], csq);
        }
    }
}

// ---------------- K6: h = relu(h2*scale + shift + h_prev); scale/shift from raw sums ----
template<bool LAST>
__global__ __launch_bounds__(256) void k_bn_apply(
    const unsigned short* __restrict__ h2b, const float* __restrict__ stats,
    const float* __restrict__ gamma, const float* __restrict__ beta,
    unsigned short* __restrict__ hb, float* __restrict__ h)
{
    __shared__ float ssc[H], ssh[H];
    int tid = threadIdx.x;
    if (tid < H) {
        float s = stats[tid], sq = stats[H + tid];
        float mean = s / (float)N_NODES;
        float var = fmaxf(sq / (float)N_NODES - mean * mean, 0.f);
        float scale = gamma[tid] * rsqrtf(var + EPSV);
        ssc[tid] = scale;
        ssh[tid] = beta[tid] - mean * scale;
    }
    __syncthreads();
    size_t base = ((size_t)blockIdx.x * 256 + tid) * 8;
    int c = (int)(base & 127);
    uint4 hv2 = *(const uint4*)(h2b + base);
    uint4 hvp = *(const uint4*)(hb + base);
    unsigned int u2[4] = {hv2.x, hv2.y, hv2.z, hv2.w};
    unsigned int up[4] = {hvp.x, hvp.y, hvp.z, hvp.w};
    float o[8];
#pragma unroll
    for (int k = 0; k < 4; ++k) {
        float vlo = bf2f(u2[k] & 0xffffu), vhi = bf2f(u2[k] >> 16);
        float plo = bf2f(up[k] & 0xffffu), phi = bf2f(up[k] >> 16);
        o[2 * k]     = fmaxf(vlo * ssc[c + 2 * k]     + ssh[c + 2 * k]     + plo, 0.f);
        o[2 * k + 1] = fmaxf(vhi * ssc[c + 2 * k + 1] + ssh[c + 2 * k + 1] + phi, 0.f);
    }
    uint4 pk;
    pk.x = (unsigned int)f2bf(o[0]) | ((unsigned int)f2bf(o[1]) << 16);
    pk.y = (unsigned int)f2bf(o[2]) | ((unsigned int)f2bf(o[3]) << 16);
    pk.z = (unsigned int)f2bf(o[4]) | ((unsigned int)f2bf(o[5]) << 16);
    pk.w = (unsigned int)f2bf(o[6]) | ((unsigned int)f2bf(o[7]) << 16);
    *(uint4*)(hb + base) = pk;
    if (LAST) {
        *(float4*)(h + base)     = make_float4(o[0], o[1], o[2], o[3]);
        *(float4*)(h + base + 4) = make_float4(o[4], o[5], o[6], o[7]);
    }
}

// ---------------- K7: fused gate MFMA + segment softmax + weighted pool ----------------
// block = 1 graph = 64 nodes, 256 threads (4 waves)
__global__ __launch_bounds__(256) void k_gate_pool(
    const unsigned short* __restrict__ hb, const float* __restrict__ h,
    const unsigned short* __restrict__ gwp,
    const float* __restrict__ b1, const float* __restrict__ w2,
    const float* __restrict__ b2, float* __restrict__ pooled)
{
    __shared__ float Red[256];
    __shared__ float al[64];
    int tid = threadIdx.x;
    int w = tid >> 6, l = tid & 63;
    int lr = l & 15, hi = l >> 4;
    int g = blockIdx.x;
    int n0 = g * SEG;

    f32x4 acc[4][2];
#pragma unroll
    for (int rb = 0; rb < 4; ++rb) {
        acc[rb][0] = (f32x4){0.f, 0.f, 0.f, 0.f};
        acc[rb][1] = (f32x4){0.f, 0.f, 0.f, 0.f};
    }
    const bf16x8* wv = (const bf16x8*)gwp;
#pragma unroll
    for (int ks = 0; ks < 4; ++ks) {
        bf16x8 bb0 = wv[((2 * w + 0) * 4 + ks) * 64 + l];
        bf16x8 bb1 = wv[((2 * w + 1) * 4 + ks) * 64 + l];
#pragma unroll
        for (int rb = 0; rb < 4; ++rb) {
            bf16x8 a = *(const bf16x8*)(hb + (size_t)(n0 + rb * 16 + lr) * H + ks * 32 + hi * 8);
            acc[rb][0] = __builtin_amdgcn_mfma_f32_16x16x32_bf16(a, bb0, acc[rb][0], 0, 0, 0);
            acc[rb][1] = __builtin_amdgcn_mfma_f32_16x16x32_bf16(a, bb1, acc[rb][1], 0, 0, 0);
        }
    }
    // gate row-partials: relu(v + b1) . w2 over this wave's 32 cols
    int col0 = w * 32 + lr, col1 = w * 32 + 16 + lr;
    float b10 = b1[col0], b11 = b1[col1];
    float w20 = w2[col0], w21 = w2[col1];
    float p[4][4];
#pragma unroll
    for (int rb = 0; rb < 4; ++rb)
#pragma unroll
        for (int jj = 0; jj < 4; ++jj) {
            float v0 = fmaxf(acc[rb][0][jj] + b10, 0.f);
            float v1 = fmaxf(acc[rb][1][jj] + b11, 0.f);
            float s = v0 * w20 + v1 * w21;
            s += __shfl_xor(s, 1); s += __shfl_xor(s, 2);
            s += __shfl_xor(s, 4); s += __shfl_xor(s, 8);
            p[rb][jj] = s;
        }
    if (lr == 0) {
#pragma unroll
        for (int rb = 0; rb < 4; ++rb)
#pragma unroll
            for (int jj = 0; jj < 4; ++jj)
                Red[w * 64 + rb * 16 + hi * 4 + jj] = p[rb][jj];
    }
    __syncthreads();
    if (tid < 64) {
        float gt = Red[tid] + Red[64 + tid] + Red[128 + tid] + Red[192 + tid] + b2[0];
        float m = gt;
#pragma unroll
        for (int off = 32; off >= 1; off >>= 1) m = fmaxf(m, __shfl_xor(m, off));
        float e = expf(gt - m);
        float s = e;
#pragma unroll
        for (int off = 32; off >= 1; off >>= 1) s += __shfl_xor(s, off);
        al[tid] = e / s;
    }
    __syncthreads();
    // weighted pool over fp32 h
    int c = tid & 127, half = tid >> 7;
    float pp = 0.f;
    const float* hbase = h + (size_t)n0 * H;
    for (int j = half * 32; j < half * 32 + 32; ++j)
        pp += al[j] * hbase[(size_t)j * H + c];
    Red[tid] = pp;
    __syncthreads();
    if (tid < 128) pooled[(size_t)g * H + tid] = Red[tid] + Red[128 + tid];
}

// ---------------- K9: global_embedding = [pooled, gf] @ gi_w + gi_b ----------------
__global__ __launch_bounds__(128) void k_final(
    const float* __restrict__ pooled, const float* __restrict__ gfeat,
    const float* __restrict__ gf_w, const float* __restrict__ gf_b,
    const float* __restrict__ gi_w, const float* __restrict__ gi_b,
    float* __restrict__ out)
{
    int g = blockIdx.x, c = threadIdx.x;
    __shared__ float prow[H], gfs[H];
    prow[c] = pooled[(size_t)g * H + c];
    float gv = gf_b[c];
    const float* gr = gfeat + (size_t)g * GF;
#pragma unroll
    for (int k = 0; k < GF; ++k) gv += gr[k] * gf_w[k * H + c];
    gfs[c] = gv;
    __syncthreads();
    float acc = gi_b[c];
    for (int k = 0; k < H; ++k) acc += prow[k] * gi_w[k * H + c];
    for (int k = 0; k < H; ++k) acc += gfs[k] * gi_w[(H + k) * H + c];
    out[(size_t)N_NODES * H + (size_t)g * H + c] = acc;
}

extern "C" void kernel_launch(void* const* d_in, const int* in_sizes, int n_in,
                              void* d_out, int out_size, void* d_ws, size_t ws_size,
                              hipStream_t stream)
{
    const float* x       = (const float*)d_in[0];
    const int*   ei      = (const int*)d_in[1];
    const float* eattr   = (const float*)d_in[2];
    const float* gfeat   = (const float*)d_in[3];
    // d_in[4] = batch (unused; batch[n] == n/64)
    const float* node_w  = (const float*)d_in[5];
    const float* node_b  = (const float*)d_in[6];
    const float* edge_w  = (const float*)d_in[7];
    const float* edge_b  = (const float*)d_in[8];
    const float* rel_w   = (const float*)d_in[9];
    const float* rel_b   = (const float*)d_in[10];
    const float* root_w  = (const float*)d_in[11];
    const float* bn_g    = (const float*)d_in[12];
    const float* bn_b    = (const float*)d_in[13];
    const float* gate_w1 = (const float*)d_in[14];
    const float* gate_b1 = (const float*)d_in[15];
    const float* gate_w2 = (const float*)d_in[16];
    const float* gate_b2 = (const float*)d_in[17];
    const float* gf_w    = (const float*)d_in[18];
    const float* gf_b    = (const float*)d_in[19];
    const float* gi_w    = (const float*)d_in[20];
    const float* gi_b    = (const float*)d_in[21];

    float* h   = (float*)d_out;                          // [N,H] output 0 (written by last layer)
    float* out = (float*)d_out;

    unsigned short* h2b  = (unsigned short*)d_ws;        // [N,H] bf16
    unsigned short* hb   = h2b + (size_t)N_NODES * H;    // [N,H] bf16 live h
    unsigned short* wpck = hb + (size_t)N_NODES * H;     // [L][8][8][64][8] = 384KB
    unsigned short* gwp  = wpck + (size_t)LAYERS * 32768;// [8][4][64][8] = 32KB
    float* stats  = (float*)(gwp + 16384);               // [L][256]
    float* pooled = stats + LAYERS * 256;                // [G,H]
    int*   deg    = (int*)(pooled + (size_t)N_GRAPH * H);
    int*   rowptr = deg + N_NODES;                       // N+4
    int*   cursor = rowptr + N_NODES + 4;
    int*   bsum   = cursor + N_NODES;
    int*   boff   = bsum + NB_SCAN;
    int2*  pairs  = (int2*)(boff + NB_SCAN);             // [E] (src, edge_id)
    int*   rowtmp = cursor;                              // alias ok (scan3 reads then writes same idx)

    // ---- CSR build + weight repack (once per launch) ----
    hipMemsetAsync(deg, 0, N_NODES * sizeof(int), stream);
    k_deg<<<(N_EDGES + 255) / 256, 256, 0, stream>>>(ei, deg);
    k_scan1<<<NB_SCAN, 256, 0, stream>>>(deg, rowtmp, bsum);
    k_scan2<<<1, 256, 0, stream>>>(bsum, boff);
    k_scan3<<<NB_SCAN, 256, 0, stream>>>(rowtmp, boff, rowptr, cursor);
    k_scatter<<<(N_EDGES + 255) / 256, 256, 0, stream>>>(ei, cursor, pairs);
    k_wpack<<<LAYERS * 64, 64, 0, stream>>>(rel_w, root_w, wpck);
    k_wpack_gate<<<32, 64, 0, stream>>>(gate_w1, gwp);

    k_init_h<<<N_NODES * 32 / 256, 256, 0, stream>>>(x, node_w, node_b, hb);
    hipMemsetAsync(stats, 0, LAYERS * 256 * sizeof(float), stream);

    for (int i = 0; i < LAYERS; ++i) {
        k_layer<<<N_NODES / 64, 256, 0, stream>>>(
            rowptr, pairs, eattr, edge_w, edge_b, hb,
            wpck + (size_t)i * 32768, rel_b + (size_t)i * H,
            h2b, stats + i * 256);
        if (i < LAYERS - 1)
            k_bn_apply<false><<<N_NODES * H / 8 / 256, 256, 0, stream>>>(
                h2b, stats + i * 256, bn_g + (size_t)i * H, bn_b + (size_t)i * H, hb, h);
        else
            k_bn_apply<true><<<N_NODES * H / 8 / 256, 256, 0, stream>>>(
                h2b, stats + i * 256, bn_g + (size_t)i * H, bn_b + (size_t)i * H, hb, h);
    }

    k_gate_pool<<<N_GRAPH, 256, 0, stream>>>(hb, h, gwp, gate_b1, gate_w2, gate_b2, pooled);
    k_final<<<N_GRAPH, H, 0, stream>>>(pooled, gfeat, gf_w, gf_b, gi_w, gi_b, out);
}

// Round 5
// 1421.820 us; speedup vs baseline: 2.2405x; 1.0056x over previous
//
#include <hip/hip_runtime.h>
#include <math.h>

#define N_NODES 204800
#define N_EDGES 600000
#define N_GRAPH 3200
#define H 128
#define NF 16
#define EF 5
#define GF 8
#define LAYERS 6
#define SEG 64
#define EPSV 1e-5f
#define NB_SCAN 800   // N_NODES / 256

typedef __attribute__((ext_vector_type(8))) short bf16x8;
typedef __attribute__((ext_vector_type(4))) float f32x4;

__device__ inline float bf2f(unsigned int u) {            // low 16 bits = bf16
    return __builtin_bit_cast(float, u << 16);
}
__device__ inline unsigned short f2bf(float f) {          // RNE
    unsigned int u = __builtin_bit_cast(unsigned int, f);
    u += 0x7fffu + ((u >> 16) & 1u);
    return (unsigned short)(u >> 16);
}

// ---------------- K1: hb = bf16(x @ node_w + node_b) ----------------
__global__ __launch_bounds__(256) void k_init_h(
    const float* __restrict__ x, const float* __restrict__ node_w,
    const float* __restrict__ node_b, unsigned short* __restrict__ hb)
{
    int idx = blockIdx.x * 256 + threadIdx.x;   // n*32 + c4
    int n = idx >> 5, c0 = (idx & 31) * 4;
    float4 a = *(const float4*)(node_b + c0);
    const float* xr = x + n * NF;
#pragma unroll
    for (int k = 0; k < NF; ++k) {
        float xv = xr[k];
        float4 wv = *(const float4*)(node_w + k * H + c0);
        a.x += xv * wv.x; a.y += xv * wv.y; a.z += xv * wv.z; a.w += xv * wv.w;
    }
    unsigned int p0 = (unsigned int)f2bf(a.x) | ((unsigned int)f2bf(a.y) << 16);
    unsigned int p1 = (unsigned int)f2bf(a.z) | ((unsigned int)f2bf(a.w) << 16);
    *(uint2*)(hb + (size_t)n * H + c0) = make_uint2(p0, p1);
}

// ---------------- W repack: [rel|root] -> MFMA B-fragment order, bf16 ----------------
// wp[i][nb(8)][ks(8)][lane(64)][8]  ; ks 0..3 = rel (agg half), 4..7 = root (h half)
__global__ __launch_bounds__(64) void k_wpack(
    const float* __restrict__ relw, const float* __restrict__ rootw,
    unsigned short* __restrict__ wp)
{
    int bid = blockIdx.x;          // i*64 + nb*8 + ks
    int i = bid >> 6, f = bid & 63;
    int nb = f >> 3, ks = f & 7;
    int l = threadIdx.x;
    const float* src = (ks < 4) ? (relw + (size_t)i * H * H) : (rootw + (size_t)i * H * H);
    int ksl = ks & 3;
    int col = nb * 16 + (l & 15);
    int kbase = ksl * 32 + (l >> 4) * 8;
    unsigned short tmp[8];
#pragma unroll
    for (int m = 0; m < 8; ++m)
        tmp[m] = f2bf(src[(size_t)(kbase + m) * H + col]);
    *(uint4*)(wp + ((size_t)bid * 64 + l) * 8) = *(uint4*)tmp;
}

// gate_w1 pack: gwp[nb(8)][ks(4)][lane(64)][8]
__global__ __launch_bounds__(64) void k_wpack_gate(
    const float* __restrict__ gw1, unsigned short* __restrict__ gwp)
{
    int bid = blockIdx.x;          // nb*4 + ks
    int nb = bid >> 2, ks = bid & 3;
    int l = threadIdx.x;
    int col = nb * 16 + (l & 15);
    int kbase = ks * 32 + (l >> 4) * 8;
    unsigned short tmp[8];
#pragma unroll
    for (int m = 0; m < 8; ++m)
        tmp[m] = f2bf(gw1[(size_t)(kbase + m) * H + col]);
    *(uint4*)(gwp + ((size_t)bid * 64 + l) * 8) = *(uint4*)tmp;
}

// ---------------- CSR build: deg -> scan -> scatter ----------------
__global__ __launch_bounds__(256) void k_deg(const int* __restrict__ ei, int* __restrict__ deg)
{
    int e = blockIdx.x * 256 + threadIdx.x;
    if (e < N_EDGES) atomicAdd(&deg[ei[N_EDGES + e]], 1);
}

__global__ __launch_bounds__(256) void k_scan1(
    const int* __restrict__ deg, int* __restrict__ rowtmp, int* __restrict__ bsum)
{
    __shared__ int sh[256];
    int t = threadIdx.x;
    int i = blockIdx.x * 256 + t;
    int v = deg[i];
    sh[t] = v;
    __syncthreads();
    for (int off = 1; off < 256; off <<= 1) {
        int a = (t >= off) ? sh[t - off] : 0;
        __syncthreads();
        sh[t] += a;
        __syncthreads();
    }
    rowtmp[i] = sh[t] - v;                 // exclusive
    if (t == 255) bsum[blockIdx.x] = sh[255];
}

__global__ void k_scan2(int* __restrict__ bsum, int* __restrict__ boff)  // 1 block x 256
{
    __shared__ int sh[256];
    __shared__ int carry;
    int t = threadIdx.x;
    if (t == 0) carry = 0;
    __syncthreads();
    for (int base = 0; base < NB_SCAN; base += 256) {
        int i = base + t;
        int v = (i < NB_SCAN) ? bsum[i] : 0;
        sh[t] = v;
        __syncthreads();
        for (int off = 1; off < 256; off <<= 1) {
            int a = (t >= off) ? sh[t - off] : 0;
            __syncthreads();
            sh[t] += a;
            __syncthreads();
        }
        if (i < NB_SCAN) boff[i] = carry + sh[t] - v;
        __syncthreads();
        if (t == 0) carry += sh[255];
        __syncthreads();
    }
}

__global__ __launch_bounds__(256) void k_scan3(
    const int* __restrict__ rowtmp, const int* __restrict__ boff,
    int* __restrict__ rowptr, int* __restrict__ cursor)
{
    int i = blockIdx.x * 256 + threadIdx.x;
    int r = rowtmp[i] + boff[blockIdx.x];
    rowptr[i] = r;
    cursor[i] = r;
    if (i == 0) rowptr[N_NODES] = N_EDGES;
}

__global__ __launch_bounds__(256) void k_scatter(
    const int* __restrict__ ei, int* __restrict__ cursor, int2* __restrict__ pairs)
{
    int e = blockIdx.x * 256 + threadIdx.x;
    if (e >= N_EDGES) return;
    int d = ei[N_EDGES + e];
    int pos = atomicAdd(&cursor[d], 1);
    pairs[pos] = make_int2(ei[e], e);      // (src, edge_id)
}

// ---------------- K3: pull-mode aggregation, bf16 in/out, 1 wave per node ----------------
__global__ __launch_bounds__(256) void k_agg(
    const int* __restrict__ rowptr, const int2* __restrict__ pairs,
    const float* __restrict__ eattr,
    const float* __restrict__ edge_w, const float* __restrict__ edge_b,
    const unsigned short* __restrict__ hb, unsigned short* __restrict__ aggb)
{
    int w = threadIdx.x >> 6, l = threadIdx.x & 63;
    int n = blockIdx.x * 4 + w;
    float2 ew2[EF];
#pragma unroll
    for (int k = 0; k < EF; ++k) ew2[k] = ((const float2*)(edge_w + k * H))[l];
    float2 eb2 = ((const float2*)edge_b)[l];
    float a0 = 0.f, a1 = 0.f;
    int j = rowptr[n], j1 = rowptr[n + 1];
    for (; j + 2 <= j1; j += 2) {
        int2 pa = pairs[j], pb = pairs[j + 1];
        const float* ara = eattr + (size_t)pa.y * EF;
        const float* arb = eattr + (size_t)pb.y * EF;
        unsigned int hva = *(const unsigned int*)(hb + (size_t)pa.x * H + 2 * l);
        unsigned int hvb = *(const unsigned int*)(hb + (size_t)pb.x * H + 2 * l);
        float ea0 = eb2.x, ea1 = eb2.y, fb0 = eb2.x, fb1 = eb2.y;
#pragma unroll
        for (int k = 0; k < EF; ++k) {
            float va = ara[k], vb = arb[k];
            ea0 += va * ew2[k].x; ea1 += va * ew2[k].y;
            fb0 += vb * ew2[k].x; fb1 += vb * ew2[k].y;
        }
        a0 += bf2f(hva & 0xffffu) * ea0 + bf2f(hvb & 0xffffu) * fb0;
        a1 += bf2f(hva >> 16) * ea1 + bf2f(hvb >> 16) * fb1;
    }
    if (j < j1) {
        int2 pa = pairs[j];
        const float* ara = eattr + (size_t)pa.y * EF;
        unsigned int hva = *(const unsigned int*)(hb + (size_t)pa.x * H + 2 * l);
        float ea0 = eb2.x, ea1 = eb2.y;
#pragma unroll
        for (int k = 0; k < EF; ++k) {
            float va = ara[k];
            ea0 += va * ew2[k].x; ea1 += va * ew2[k].y;
        }
        a0 += bf2f(hva & 0xffffu) * ea0;
        a1 += bf2f(hva >> 16) * ea1;
    }
    unsigned int pk = (unsigned int)f2bf(a0) | ((unsigned int)f2bf(a1) << 16);
    *(unsigned int*)(aggb + (size_t)n * H + 2 * l) = pk;
}

// ---------------- K4: MFMA dual-GEMM + BN col sums -> dedicated h2b ----------------
// block = 256 (4 waves); tile 64 rows x 128 cols; wave w: all 64 rows x cols [w*32, w*32+32)
__global__ __launch_bounds__(256) void k_gemm_mfma(
    const unsigned short* __restrict__ aggb,
    const unsigned short* __restrict__ hb,
    const unsigned short* __restrict__ wp,      // this layer's 64KB packed [rel|root]
    const float* __restrict__ relb,
    unsigned short* __restrict__ h2b,
    float* __restrict__ stats)                  // this layer's [256] (sum, sumsq)
{
    int tid = threadIdx.x;
    int w = tid >> 6, l = tid & 63;
    int n0 = blockIdx.x * 64;
    int lr = l & 15, hi = l >> 4;

    f32x4 acc[4][2];
#pragma unroll
    for (int rb = 0; rb < 4; ++rb) {
        acc[rb][0] = (f32x4){0.f, 0.f, 0.f, 0.f};
        acc[rb][1] = (f32x4){0.f, 0.f, 0.f, 0.f};
    }

    const bf16x8* wv = (const bf16x8*)wp;
#pragma unroll
    for (int ks = 0; ks < 4; ++ks) {            // agg half
        bf16x8 b0 = wv[((2 * w + 0) * 8 + ks) * 64 + l];
        bf16x8 b1 = wv[((2 * w + 1) * 8 + ks) * 64 + l];
#pragma unroll
        for (int rb = 0; rb < 4; ++rb) {
            bf16x8 a = *(const bf16x8*)(aggb + (size_t)(n0 + rb * 16 + lr) * H + ks * 32 + hi * 8);
            acc[rb][0] = __builtin_amdgcn_mfma_f32_16x16x32_bf16(a, b0, acc[rb][0], 0, 0, 0);
            acc[rb][1] = __builtin_amdgcn_mfma_f32_16x16x32_bf16(a, b1, acc[rb][1], 0, 0, 0);
        }
    }
#pragma unroll
    for (int ks = 0; ks < 4; ++ks) {            // root half
        bf16x8 b0 = wv[((2 * w + 0) * 8 + 4 + ks) * 64 + l];
        bf16x8 b1 = wv[((2 * w + 1) * 8 + 4 + ks) * 64 + l];
#pragma unroll
        for (int rb = 0; rb < 4; ++rb) {
            bf16x8 a = *(const bf16x8*)(hb + (size_t)(n0 + rb * 16 + lr) * H + ks * 32 + hi * 8);
            acc[rb][0] = __builtin_amdgcn_mfma_f32_16x16x32_bf16(a, b0, acc[rb][0], 0, 0, 0);
            acc[rb][1] = __builtin_amdgcn_mfma_f32_16x16x32_bf16(a, b1, acc[rb][1], 0, 0, 0);
        }
    }

    // epilogue: bias, bf16 store, BN col sums
#pragma unroll
    for (int nbl = 0; nbl < 2; ++nbl) {
        int col = w * 32 + nbl * 16 + lr;
        float bs = relb[col];
        float csum = 0.f, csq = 0.f;
#pragma unroll
        for (int rb = 0; rb < 4; ++rb) {
#pragma unroll
            for (int jj = 0; jj < 4; ++jj) {
                float v = acc[rb][nbl][jj] + bs;
                h2b[(size_t)(n0 + rb * 16 + hi * 4 + jj) * H + col] = f2bf(v);
                csum += v; csq += v * v;
            }
        }
        csum += __shfl_xor(csum, 16); csum += __shfl_xor(csum, 32);
        csq  += __shfl_xor(csq, 16);  csq  += __shfl_xor(csq, 32);
        if (hi == 0) {
            atomicAdd(&stats[col], csum);
            atomicAdd(&stats[H + col], csq);
        }
    }
}

// ---------------- K6: h = relu(h2*scale + shift + h_prev); scale/shift from raw sums ----
template<bool LAST>
__global__ __launch_bounds__(256) void k_bn_apply(
    const unsigned short* __restrict__ h2b, const float* __restrict__ stats,
    const float* __restrict__ gamma, const float* __restrict__ beta,
    unsigned short* __restrict__ hb, float* __restrict__ h)
{
    __shared__ float ssc[H], ssh[H];
    int tid = threadIdx.x;
    if (tid < H) {
        float s = stats[tid], sq = stats[H + tid];
        float mean = s / (float)N_NODES;
        float var = fmaxf(sq / (float)N_NODES - mean * mean, 0.f);
        float scale = gamma[tid] * rsqrtf(var + EPSV);
        ssc[tid] = scale;
        ssh[tid] = beta[tid] - mean * scale;
    }
    __syncthreads();
    size_t base = ((size_t)blockIdx.x * 256 + tid) * 8;
    int c = (int)(base & 127);
    uint4 hv2 = *(const uint4*)(h2b + base);
    uint4 hvp = *(const uint4*)(hb + base);
    unsigned int u2[4] = {hv2.x, hv2.y, hv2.z, hv2.w};
    unsigned int up[4] = {hvp.x, hvp.y, hvp.z, hvp.w};
    float o[8];
#pragma unroll
    for (int k = 0; k < 4; ++k) {
        float vlo = bf2f(u2[k] & 0xffffu), vhi = bf2f(u2[k] >> 16);
        float plo = bf2f(up[k] & 0xffffu), phi = bf2f(up[k] >> 16);
        o[2 * k]     = fmaxf(vlo * ssc[c + 2 * k]     + ssh[c + 2 * k]     + plo, 0.f);
        o[2 * k + 1] = fmaxf(vhi * ssc[c + 2 * k + 1] + ssh[c + 2 * k + 1] + phi, 0.f);
    }
    uint4 pk;
    pk.x = (unsigned int)f2bf(o[0]) | ((unsigned int)f2bf(o[1]) << 16);
    pk.y = (unsigned int)f2bf(o[2]) | ((unsigned int)f2bf(o[3]) << 16);
    pk.z = (unsigned int)f2bf(o[4]) | ((unsigned int)f2bf(o[5]) << 16);
    pk.w = (unsigned int)f2bf(o[6]) | ((unsigned int)f2bf(o[7]) << 16);
    *(uint4*)(hb + base) = pk;
    if (LAST) {
        *(float4*)(h + base)     = make_float4(o[0], o[1], o[2], o[3]);
        *(float4*)(h + base + 4) = make_float4(o[4], o[5], o[6], o[7]);
    }
}

// ---------------- K7: fused gate MFMA + segment softmax + weighted pool ----------------
// block = 1 graph = 64 nodes, 256 threads (4 waves)
__global__ __launch_bounds__(256) void k_gate_pool(
    const unsigned short* __restrict__ hb, const float* __restrict__ h,
    const unsigned short* __restrict__ gwp,
    const float* __restrict__ b1, const float* __restrict__ w2,
    const float* __restrict__ b2, float* __restrict__ pooled)
{
    __shared__ float Red[256];
    __shared__ float al[64];
    int tid = threadIdx.x;
    int w = tid >> 6, l = tid & 63;
    int lr = l & 15, hi = l >> 4;
    int g = blockIdx.x;
    int n0 = g * SEG;

    f32x4 acc[4][2];
#pragma unroll
    for (int rb = 0; rb < 4; ++rb) {
        acc[rb][0] = (f32x4){0.f, 0.f, 0.f, 0.f};
        acc[rb][1] = (f32x4){0.f, 0.f, 0.f, 0.f};
    }
    const bf16x8* wv = (const bf16x8*)gwp;
#pragma unroll
    for (int ks = 0; ks < 4; ++ks) {
        bf16x8 bb0 = wv[((2 * w + 0) * 4 + ks) * 64 + l];
        bf16x8 bb1 = wv[((2 * w + 1) * 4 + ks) * 64 + l];
#pragma unroll
        for (int rb = 0; rb < 4; ++rb) {
            bf16x8 a = *(const bf16x8*)(hb + (size_t)(n0 + rb * 16 + lr) * H + ks * 32 + hi * 8);
            acc[rb][0] = __builtin_amdgcn_mfma_f32_16x16x32_bf16(a, bb0, acc[rb][0], 0, 0, 0);
            acc[rb][1] = __builtin_amdgcn_mfma_f32_16x16x32_bf16(a, bb1, acc[rb][1], 0, 0, 0);
        }
    }
    // gate row-partials: relu(v + b1) . w2 over this wave's 32 cols
    int col0 = w * 32 + lr, col1 = w * 32 + 16 + lr;
    float b10 = b1[col0], b11 = b1[col1];
    float w20 = w2[col0], w21 = w2[col1];
    float p[4][4];
#pragma unroll
    for (int rb = 0; rb < 4; ++rb)
#pragma unroll
        for (int jj = 0; jj < 4; ++jj) {
            float v0 = fmaxf(acc[rb][0][jj] + b10, 0.f);
            float v1 = fmaxf(acc[rb][1][jj] + b11, 0.f);
            float s = v0 * w20 + v1 * w21;
            s += __shfl_xor(s, 1); s += __shfl_xor(s, 2);
            s += __shfl_xor(s, 4); s += __shfl_xor(s, 8);
            p[rb][jj] = s;
        }
    if (lr == 0) {
#pragma unroll
        for (int rb = 0; rb < 4; ++rb)
#pragma unroll
            for (int jj = 0; jj < 4; ++jj)
                Red[w * 64 + rb * 16 + hi * 4 + jj] = p[rb][jj];
    }
    __syncthreads();
    if (tid < 64) {
        float gt = Red[tid] + Red[64 + tid] + Red[128 + tid] + Red[192 + tid] + b2[0];
        float m = gt;
#pragma unroll
        for (int off = 32; off >= 1; off >>= 1) m = fmaxf(m, __shfl_xor(m, off));
        float e = expf(gt - m);
        float s = e;
#pragma unroll
        for (int off = 32; off >= 1; off >>= 1) s += __shfl_xor(s, off);
        al[tid] = e / s;
    }
    __syncthreads();
    // weighted pool over fp32 h
    int c = tid & 127, half = tid >> 7;
    float pp = 0.f;
    const float* hbase = h + (size_t)n0 * H;
    for (int j = half * 32; j < half * 32 + 32; ++j)
        pp += al[j] * hbase[(size_t)j * H + c];
    Red[tid] = pp;
    __syncthreads();
    if (tid < 128) pooled[(size_t)g * H + tid] = Red[tid] + Red[128 + tid];
}

// ---------------- K9: global_embedding = [pooled, gf] @ gi_w + gi_b ----------------
__global__ __launch_bounds__(128) void k_final(
    const float* __restrict__ pooled, const float* __restrict__ gfeat,
    const float* __restrict__ gf_w, const float* __restrict__ gf_b,
    const float* __restrict__ gi_w, const float* __restrict__ gi_b,
    float* __restrict__ out)
{
    int g = blockIdx.x, c = threadIdx.x;
    __shared__ float prow[H], gfs[H];
    prow[c] = pooled[(size_t)g * H + c];
    float gv = gf_b[c];
    const float* gr = gfeat + (size_t)g * GF;
#pragma unroll
    for (int k = 0; k < GF; ++k) gv += gr[k] * gf_w[k * H + c];
    gfs[c] = gv;
    __syncthreads();
    float acc = gi_b[c];
    for (int k = 0; k < H; ++k) acc += prow[k] * gi_w[k * H + c];
    for (int k = 0; k < H; ++k) acc += gfs[k] * gi_w[(H + k) * H + c];
    out[(size_t)N_NODES * H + (size_t)g * H + c] = acc;
}

extern "C" void kernel_launch(void* const* d_in, const int* in_sizes, int n_in,
                              void* d_out, int out_size, void* d_ws, size_t ws_size,
                              hipStream_t stream)
{
    const float* x       = (const float*)d_in[0];
    const int*   ei      = (const int*)d_in[1];
    const float* eattr   = (const float*)d_in[2];
    const float* gfeat   = (const float*)d_in[3];
    // d_in[4] = batch (unused; batch[n] == n/64)
    const float* node_w  = (const float*)d_in[5];
    const float* node_b  = (const float*)d_in[6];
    const float* edge_w  = (const float*)d_in[7];
    const float* edge_b  = (const float*)d_in[8];
    const float* rel_w   = (const float*)d_in[9];
    const float* rel_b   = (const float*)d_in[10];
    const float* root_w  = (const float*)d_in[11];
    const float* bn_g    = (const float*)d_in[12];
    const float* bn_b    = (const float*)d_in[13];
    const float* gate_w1 = (const float*)d_in[14];
    const float* gate_b1 = (const float*)d_in[15];
    const float* gate_w2 = (const float*)d_in[16];
    const float* gate_b2 = (const float*)d_in[17];
    const float* gf_w    = (const float*)d_in[18];
    const float* gf_b    = (const float*)d_in[19];
    const float* gi_w    = (const float*)d_in[20];
    const float* gi_b    = (const float*)d_in[21];

    float* h   = (float*)d_out;                          // [N,H] output 0 (written by last layer)
    float* out = (float*)d_out;

    unsigned short* h2b  = (unsigned short*)d_ws;        // [N,H] bf16
    unsigned short* hb   = h2b + (size_t)N_NODES * H;    // [N,H] bf16 live h
    unsigned short* aggb = hb + (size_t)N_NODES * H;     // [N,H] bf16 aggregate
    unsigned short* wpck = aggb + (size_t)N_NODES * H;   // [L][8][8][64][8] = 384KB
    unsigned short* gwp  = wpck + (size_t)LAYERS * 32768;// [8][4][64][8] = 32KB
    float* stats  = (float*)(gwp + 16384);               // [L][256]
    float* pooled = stats + LAYERS * 256;                // [G,H]
    int*   deg    = (int*)(pooled + (size_t)N_GRAPH * H);
    int*   rowptr = deg + N_NODES;                       // N+4
    int*   cursor = rowptr + N_NODES + 4;
    int*   bsum   = cursor + N_NODES;
    int*   boff   = bsum + NB_SCAN;
    int2*  pairs  = (int2*)(boff + NB_SCAN);             // [E] (src, edge_id)
    int*   rowtmp = cursor;                              // alias ok (scan3 reads then writes same idx)

    // ---- CSR build + weight repack (once per launch) ----
    hipMemsetAsync(deg, 0, N_NODES * sizeof(int), stream);
    k_deg<<<(N_EDGES + 255) / 256, 256, 0, stream>>>(ei, deg);
    k_scan1<<<NB_SCAN, 256, 0, stream>>>(deg, rowtmp, bsum);
    k_scan2<<<1, 256, 0, stream>>>(bsum, boff);
    k_scan3<<<NB_SCAN, 256, 0, stream>>>(rowtmp, boff, rowptr, cursor);
    k_scatter<<<(N_EDGES + 255) / 256, 256, 0, stream>>>(ei, cursor, pairs);
    k_wpack<<<LAYERS * 64, 64, 0, stream>>>(rel_w, root_w, wpck);
    k_wpack_gate<<<32, 64, 0, stream>>>(gate_w1, gwp);

    k_init_h<<<N_NODES * 32 / 256, 256, 0, stream>>>(x, node_w, node_b, hb);
    hipMemsetAsync(stats, 0, LAYERS * 256 * sizeof(float), stream);

    for (int i = 0; i < LAYERS; ++i) {
        k_agg<<<N_NODES / 4, 256, 0, stream>>>(rowptr, pairs, eattr, edge_w, edge_b, hb, aggb);
        k_gemm_mfma<<<N_NODES / 64, 256, 0, stream>>>(
            aggb, hb, wpck + (size_t)i * 32768, rel_b + (size_t)i * H,
            h2b, stats + i * 256);
        if (i < LAYERS - 1)
            k_bn_apply<false><<<N_NODES * H / 8 / 256, 256, 0, stream>>>(
                h2b, stats + i * 256, bn_g + (size_t)i * H, bn_b + (size_t)i * H, hb, h);
        else
            k_bn_apply<true><<<N_NODES * H / 8 / 256, 256, 0, stream>>>(
                h2b, stats + i * 256, bn_g + (size_t)i * H, bn_b + (size_t)i * H, hb, h);
    }

    k_gate_pool<<<N_GRAPH, 256, 0, stream>>>(hb, h, gwp, gate_b1, gate_w2, gate_b2, pooled);
    k_final<<<N_GRAPH, H, 0, stream>>>(pooled, gfeat, gf_w, gf_b, gi_w, gi_b, out);
}

// Round 6
// 1328.149 us; speedup vs baseline: 2.3985x; 1.0705x over previous
//
#include <hip/hip_runtime.h>
#include <math.h>

#define N_NODES 204800
#define N_EDGES 600000
#define N_GRAPH 3200
#define H 128
#define NF 16
#define EF 5
#define GF 8
#define LAYERS 6
#define SEG 64
#define EPSV 1e-5f
#define NB_SCAN 800   // N_NODES / 256

typedef __attribute__((ext_vector_type(8))) short bf16x8;
typedef __attribute__((ext_vector_type(4))) float f32x4;

__device__ inline float bf2f(unsigned int u) {            // low 16 bits = bf16
    return __builtin_bit_cast(float, u << 16);
}
__device__ inline unsigned short f2bf(float f) {          // RNE
    unsigned int u = __builtin_bit_cast(unsigned int, f);
    u += 0x7fffu + ((u >> 16) & 1u);
    return (unsigned short)(u >> 16);
}
__device__ inline float uif(unsigned int u) { return __builtin_bit_cast(float, u); }

// ---------------- K1: hb = bf16(x @ node_w + node_b) ----------------
__global__ __launch_bounds__(256) void k_init_h(
    const float* __restrict__ x, const float* __restrict__ node_w,
    const float* __restrict__ node_b, unsigned short* __restrict__ hb)
{
    int idx = blockIdx.x * 256 + threadIdx.x;   // n*32 + c4
    int n = idx >> 5, c0 = (idx & 31) * 4;
    float4 a = *(const float4*)(node_b + c0);
    const float* xr = x + n * NF;
#pragma unroll
    for (int k = 0; k < NF; ++k) {
        float xv = xr[k];
        float4 wv = *(const float4*)(node_w + k * H + c0);
        a.x += xv * wv.x; a.y += xv * wv.y; a.z += xv * wv.z; a.w += xv * wv.w;
    }
    unsigned int p0 = (unsigned int)f2bf(a.x) | ((unsigned int)f2bf(a.y) << 16);
    unsigned int p1 = (unsigned int)f2bf(a.z) | ((unsigned int)f2bf(a.w) << 16);
    *(uint2*)(hb + (size_t)n * H + c0) = make_uint2(p0, p1);
}

// ---------------- W repack: [rel|root] -> MFMA B-fragment order, bf16 ----------------
// wp[i][nb(8)][ks(8)][lane(64)][8]  ; ks 0..3 = rel (agg half), 4..7 = root (h half)
__global__ __launch_bounds__(64) void k_wpack(
    const float* __restrict__ relw, const float* __restrict__ rootw,
    unsigned short* __restrict__ wp)
{
    int bid = blockIdx.x;          // i*64 + nb*8 + ks
    int i = bid >> 6, f = bid & 63;
    int nb = f >> 3, ks = f & 7;
    int l = threadIdx.x;
    const float* src = (ks < 4) ? (relw + (size_t)i * H * H) : (rootw + (size_t)i * H * H);
    int ksl = ks & 3;
    int col = nb * 16 + (l & 15);
    int kbase = ksl * 32 + (l >> 4) * 8;
    unsigned short tmp[8];
#pragma unroll
    for (int m = 0; m < 8; ++m)
        tmp[m] = f2bf(src[(size_t)(kbase + m) * H + col]);
    *(uint4*)(wp + ((size_t)bid * 64 + l) * 8) = *(uint4*)tmp;
}

// gate_w1 pack: gwp[nb(8)][ks(4)][lane(64)][8]
__global__ __launch_bounds__(64) void k_wpack_gate(
    const float* __restrict__ gw1, unsigned short* __restrict__ gwp)
{
    int bid = blockIdx.x;          // nb*4 + ks
    int nb = bid >> 2, ks = bid & 3;
    int l = threadIdx.x;
    int col = nb * 16 + (l & 15);
    int kbase = ks * 32 + (l >> 4) * 8;
    unsigned short tmp[8];
#pragma unroll
    for (int m = 0; m < 8; ++m)
        tmp[m] = f2bf(gw1[(size_t)(kbase + m) * H + col]);
    *(uint4*)(gwp + ((size_t)bid * 64 + l) * 8) = *(uint4*)tmp;
}

// ---------------- CSR build: deg -> scan -> scatter ----------------
__global__ __launch_bounds__(256) void k_deg(const int* __restrict__ ei, int* __restrict__ deg)
{
    int e = blockIdx.x * 256 + threadIdx.x;
    if (e < N_EDGES) atomicAdd(&deg[ei[N_EDGES + e]], 1);
}

__global__ __launch_bounds__(256) void k_scan1(
    const int* __restrict__ deg, int* __restrict__ rowtmp, int* __restrict__ bsum)
{
    __shared__ int sh[256];
    int t = threadIdx.x;
    int i = blockIdx.x * 256 + t;
    int v = deg[i];
    sh[t] = v;
    __syncthreads();
    for (int off = 1; off < 256; off <<= 1) {
        int a = (t >= off) ? sh[t - off] : 0;
        __syncthreads();
        sh[t] += a;
        __syncthreads();
    }
    rowtmp[i] = sh[t] - v;                 // exclusive
    if (t == 255) bsum[blockIdx.x] = sh[255];
}

__global__ void k_scan2(int* __restrict__ bsum, int* __restrict__ boff)  // 1 block x 256
{
    __shared__ int sh[256];
    __shared__ int carry;
    int t = threadIdx.x;
    if (t == 0) carry = 0;
    __syncthreads();
    for (int base = 0; base < NB_SCAN; base += 256) {
        int i = base + t;
        int v = (i < NB_SCAN) ? bsum[i] : 0;
        sh[t] = v;
        __syncthreads();
        for (int off = 1; off < 256; off <<= 1) {
            int a = (t >= off) ? sh[t - off] : 0;
            __syncthreads();
            sh[t] += a;
            __syncthreads();
        }
        if (i < NB_SCAN) boff[i] = carry + sh[t] - v;
        __syncthreads();
        if (t == 0) carry += sh[255];
        __syncthreads();
    }
}

__global__ __launch_bounds__(256) void k_scan3(
    const int* __restrict__ rowtmp, const int* __restrict__ boff,
    int* __restrict__ rowptr, int* __restrict__ cursor)
{
    int i = blockIdx.x * 256 + threadIdx.x;
    int r = rowtmp[i] + boff[blockIdx.x];
    rowptr[i] = r;
    cursor[i] = r;
    if (i == 0) rowptr[N_NODES] = N_EDGES;
}

// scatter 32B records: {src, ea0..ea4, pad, pad}
__global__ __launch_bounds__(256) void k_scatter(
    const int* __restrict__ ei, const float* __restrict__ eattr,
    int* __restrict__ cursor, uint4* __restrict__ recs)
{
    int e = blockIdx.x * 256 + threadIdx.x;
    if (e >= N_EDGES) return;
    int d = ei[N_EDGES + e];
    const float* ar = eattr + (size_t)e * EF;
    float c0 = ar[0], c1 = ar[1], c2 = ar[2], c3 = ar[3], c4 = ar[4];
    int pos = atomicAdd(&cursor[d], 1);
    uint4 q0, q1;
    q0.x = (unsigned int)ei[e];
    q0.y = __builtin_bit_cast(unsigned int, c0);
    q0.z = __builtin_bit_cast(unsigned int, c1);
    q0.w = __builtin_bit_cast(unsigned int, c2);
    q1.x = __builtin_bit_cast(unsigned int, c3);
    q1.y = __builtin_bit_cast(unsigned int, c4);
    q1.z = 0; q1.w = 0;
    recs[2 * (size_t)pos]     = q0;
    recs[2 * (size_t)pos + 1] = q1;
}

// ---------------- K3: pull aggregation; 2 nodes/wave, interleaved 2-edge unroll --------
#define EDGE_ONE(q0, q1, A0, A1)                                               \
    {                                                                          \
        unsigned int hv = *(const unsigned int*)(hb + (size_t)(int)(q0).x * H + 2 * l); \
        float ea0 = eb2.x, ea1 = eb2.y;                                        \
        float c0 = uif((q0).y), c1 = uif((q0).z), c2 = uif((q0).w);            \
        float c3 = uif((q1).x), c4 = uif((q1).y);                              \
        ea0 += c0 * ew2[0].x + c1 * ew2[1].x + c2 * ew2[2].x + c3 * ew2[3].x + c4 * ew2[4].x; \
        ea1 += c0 * ew2[0].y + c1 * ew2[1].y + c2 * ew2[2].y + c3 * ew2[3].y + c4 * ew2[4].y; \
        A0 += bf2f(hv & 0xffffu) * ea0;                                        \
        A1 += bf2f(hv >> 16) * ea1;                                            \
    }

__global__ __launch_bounds__(256) void k_agg(
    const int* __restrict__ rowptr, const uint4* __restrict__ recs,
    const float* __restrict__ edge_w, const float* __restrict__ edge_b,
    const unsigned short* __restrict__ hb, unsigned short* __restrict__ aggb)
{
    int w = threadIdx.x >> 6, l = threadIdx.x & 63;
    int n = blockIdx.x * 8 + w * 2;            // this wave: nodes n, n+1
    float2 ew2[EF];
#pragma unroll
    for (int k = 0; k < EF; ++k) ew2[k] = ((const float2*)(edge_w + k * H))[l];
    float2 eb2 = ((const float2*)edge_b)[l];

    int jA = rowptr[n], eA = rowptr[n + 1];
    int jB = eA,        eB = rowptr[n + 2];
    float a0 = 0.f, a1 = 0.f, b0 = 0.f, b1 = 0.f;

    // interleaved main loop: 4 independent gathers in flight
    while (jA + 2 <= eA && jB + 2 <= eB) {
        uint4 qa0 = recs[2 * jA],     qa1 = recs[2 * jA + 1];
        uint4 qb0 = recs[2 * jA + 2], qb1 = recs[2 * jA + 3];
        uint4 qc0 = recs[2 * jB],     qc1 = recs[2 * jB + 1];
        uint4 qd0 = recs[2 * jB + 2], qd1 = recs[2 * jB + 3];
        EDGE_ONE(qa0, qa1, a0, a1);
        EDGE_ONE(qb0, qb1, a0, a1);
        EDGE_ONE(qc0, qc1, b0, b1);
        EDGE_ONE(qd0, qd1, b0, b1);
        jA += 2; jB += 2;
    }
    // drain A
    while (jA + 2 <= eA) {
        uint4 qa0 = recs[2 * jA],     qa1 = recs[2 * jA + 1];
        uint4 qb0 = recs[2 * jA + 2], qb1 = recs[2 * jA + 3];
        EDGE_ONE(qa0, qa1, a0, a1);
        EDGE_ONE(qb0, qb1, a0, a1);
        jA += 2;
    }
    if (jA < eA) {
        uint4 qa0 = recs[2 * jA], qa1 = recs[2 * jA + 1];
        EDGE_ONE(qa0, qa1, a0, a1);
    }
    // drain B
    while (jB + 2 <= eB) {
        uint4 qc0 = recs[2 * jB],     qc1 = recs[2 * jB + 1];
        uint4 qd0 = recs[2 * jB + 2], qd1 = recs[2 * jB + 3];
        EDGE_ONE(qc0, qc1, b0, b1);
        EDGE_ONE(qd0, qd1, b0, b1);
        jB += 2;
    }
    if (jB < eB) {
        uint4 qc0 = recs[2 * jB], qc1 = recs[2 * jB + 1];
        EDGE_ONE(qc0, qc1, b0, b1);
    }

    unsigned int pka = (unsigned int)f2bf(a0) | ((unsigned int)f2bf(a1) << 16);
    unsigned int pkb = (unsigned int)f2bf(b0) | ((unsigned int)f2bf(b1) << 16);
    *(unsigned int*)(aggb + (size_t)n * H + 2 * l)       = pka;
    *(unsigned int*)(aggb + (size_t)(n + 1) * H + 2 * l) = pkb;
}

// ---------------- K4: MFMA dual-GEMM + BN col sums -> dedicated h2b ----------------
// block = 256 (4 waves); tile 64 rows x 128 cols; wave w: all 64 rows x cols [w*32, w*32+32)
__global__ __launch_bounds__(256) void k_gemm_mfma(
    const unsigned short* __restrict__ aggb,
    const unsigned short* __restrict__ hb,
    const unsigned short* __restrict__ wp,      // this layer's 64KB packed [rel|root]
    const float* __restrict__ relb,
    unsigned short* __restrict__ h2b,
    float* __restrict__ stats)                  // this layer's [256] (sum, sumsq)
{
    int tid = threadIdx.x;
    int w = tid >> 6, l = tid & 63;
    int n0 = blockIdx.x * 64;
    int lr = l & 15, hi = l >> 4;

    f32x4 acc[4][2];
#pragma unroll
    for (int rb = 0; rb < 4; ++rb) {
        acc[rb][0] = (f32x4){0.f, 0.f, 0.f, 0.f};
        acc[rb][1] = (f32x4){0.f, 0.f, 0.f, 0.f};
    }

    const bf16x8* wv = (const bf16x8*)wp;
#pragma unroll
    for (int ks = 0; ks < 4; ++ks) {            // agg half
        bf16x8 b0 = wv[((2 * w + 0) * 8 + ks) * 64 + l];
        bf16x8 b1 = wv[((2 * w + 1) * 8 + ks) * 64 + l];
#pragma unroll
        for (int rb = 0; rb < 4; ++rb) {
            bf16x8 a = *(const bf16x8*)(aggb + (size_t)(n0 + rb * 16 + lr) * H + ks * 32 + hi * 8);
            acc[rb][0] = __builtin_amdgcn_mfma_f32_16x16x32_bf16(a, b0, acc[rb][0], 0, 0, 0);
            acc[rb][1] = __builtin_amdgcn_mfma_f32_16x16x32_bf16(a, b1, acc[rb][1], 0, 0, 0);
        }
    }
#pragma unroll
    for (int ks = 0; ks < 4; ++ks) {            // root half
        bf16x8 b0 = wv[((2 * w + 0) * 8 + 4 + ks) * 64 + l];
        bf16x8 b1 = wv[((2 * w + 1) * 8 + 4 + ks) * 64 + l];
#pragma unroll
        for (int rb = 0; rb < 4; ++rb) {
            bf16x8 a = *(const bf16x8*)(hb + (size_t)(n0 + rb * 16 + lr) * H + ks * 32 + hi * 8);
            acc[rb][0] = __builtin_amdgcn_mfma_f32_16x16x32_bf16(a, b0, acc[rb][0], 0, 0, 0);
            acc[rb][1] = __builtin_amdgcn_mfma_f32_16x16x32_bf16(a, b1, acc[rb][1], 0, 0, 0);
        }
    }

    // epilogue: bias, bf16 store, BN col sums
#pragma unroll
    for (int nbl = 0; nbl < 2; ++nbl) {
        int col = w * 32 + nbl * 16 + lr;
        float bs = relb[col];
        float csum = 0.f, csq = 0.f;
#pragma unroll
        for (int rb = 0; rb < 4; ++rb) {
#pragma unroll
            for (int jj = 0; jj < 4; ++jj) {
                float v = acc[rb][nbl][jj] + bs;
                h2b[(size_t)(n0 + rb * 16 + hi * 4 + jj) * H + col] = f2bf(v);
                csum += v; csq += v * v;
            }
        }
        csum += __shfl_xor(csum, 16); csum += __shfl_xor(csum, 32);
        csq  += __shfl_xor(csq, 16);  csq  += __shfl_xor(csq, 32);
        if (hi == 0) {
            atomicAdd(&stats[col], csum);
            atomicAdd(&stats[H + col], csq);
        }
    }
}

// ---------------- K6: h = relu(h2*scale + shift + h_prev); scale/shift from raw sums ----
template<bool LAST>
__global__ __launch_bounds__(256) void k_bn_apply(
    const unsigned short* __restrict__ h2b, const float* __restrict__ stats,
    const float* __restrict__ gamma, const float* __restrict__ beta,
    unsigned short* __restrict__ hb, float* __restrict__ h)
{
    __shared__ float ssc[H], ssh[H];
    int tid = threadIdx.x;
    if (tid < H) {
        float s = stats[tid], sq = stats[H + tid];
        float mean = s / (float)N_NODES;
        float var = fmaxf(sq / (float)N_NODES - mean * mean, 0.f);
        float scale = gamma[tid] * rsqrtf(var + EPSV);
        ssc[tid] = scale;
        ssh[tid] = beta[tid] - mean * scale;
    }
    __syncthreads();
    size_t base = ((size_t)blockIdx.x * 256 + tid) * 8;
    int c = (int)(base & 127);
    uint4 hv2 = *(const uint4*)(h2b + base);
    uint4 hvp = *(const uint4*)(hb + base);
    unsigned int u2[4] = {hv2.x, hv2.y, hv2.z, hv2.w};
    unsigned int up[4] = {hvp.x, hvp.y, hvp.z, hvp.w};
    float o[8];
#pragma unroll
    for (int k = 0; k < 4; ++k) {
        float vlo = bf2f(u2[k] & 0xffffu), vhi = bf2f(u2[k] >> 16);
        float plo = bf2f(up[k] & 0xffffu), phi = bf2f(up[k] >> 16);
        o[2 * k]     = fmaxf(vlo * ssc[c + 2 * k]     + ssh[c + 2 * k]     + plo, 0.f);
        o[2 * k + 1] = fmaxf(vhi * ssc[c + 2 * k + 1] + ssh[c + 2 * k + 1] + phi, 0.f);
    }
    uint4 pk;
    pk.x = (unsigned int)f2bf(o[0]) | ((unsigned int)f2bf(o[1]) << 16);
    pk.y = (unsigned int)f2bf(o[2]) | ((unsigned int)f2bf(o[3]) << 16);
    pk.z = (unsigned int)f2bf(o[4]) | ((unsigned int)f2bf(o[5]) << 16);
    pk.w = (unsigned int)f2bf(o[6]) | ((unsigned int)f2bf(o[7]) << 16);
    *(uint4*)(hb + base) = pk;
    if (LAST) {
        *(float4*)(h + base)     = make_float4(o[0], o[1], o[2], o[3]);
        *(float4*)(h + base + 4) = make_float4(o[4], o[5], o[6], o[7]);
    }
}

// ---------------- K7: fused gate MFMA + segment softmax + weighted pool ----------------
// block = 1 graph = 64 nodes, 256 threads (4 waves)
__global__ __launch_bounds__(256) void k_gate_pool(
    const unsigned short* __restrict__ hb, const float* __restrict__ h,
    const unsigned short* __restrict__ gwp,
    const float* __restrict__ b1, const float* __restrict__ w2,
    const float* __restrict__ b2, float* __restrict__ pooled)
{
    __shared__ float Red[256];
    __shared__ float al[64];
    int tid = threadIdx.x;
    int w = tid >> 6, l = tid & 63;
    int lr = l & 15, hi = l >> 4;
    int g = blockIdx.x;
    int n0 = g * SEG;

    f32x4 acc[4][2];
#pragma unroll
    for (int rb = 0; rb < 4; ++rb) {
        acc[rb][0] = (f32x4){0.f, 0.f, 0.f, 0.f};
        acc[rb][1] = (f32x4){0.f, 0.f, 0.f, 0.f};
    }
    const bf16x8* wv = (const bf16x8*)gwp;
#pragma unroll
    for (int ks = 0; ks < 4; ++ks) {
        bf16x8 bb0 = wv[((2 * w + 0) * 4 + ks) * 64 + l];
        bf16x8 bb1 = wv[((2 * w + 1) * 4 + ks) * 64 + l];
#pragma unroll
        for (int rb = 0; rb < 4; ++rb) {
            bf16x8 a = *(const bf16x8*)(hb + (size_t)(n0 + rb * 16 + lr) * H + ks * 32 + hi * 8);
            acc[rb][0] = __builtin_amdgcn_mfma_f32_16x16x32_bf16(a, bb0, acc[rb][0], 0, 0, 0);
            acc[rb][1] = __builtin_amdgcn_mfma_f32_16x16x32_bf16(a, bb1, acc[rb][1], 0, 0, 0);
        }
    }
    // gate row-partials: relu(v + b1) . w2 over this wave's 32 cols
    int col0 = w * 32 + lr, col1 = w * 32 + 16 + lr;
    float b10 = b1[col0], b11 = b1[col1];
    float w20 = w2[col0], w21 = w2[col1];
    float p[4][4];
#pragma unroll
    for (int rb = 0; rb < 4; ++rb)
#pragma unroll
        for (int jj = 0; jj < 4; ++jj) {
            float v0 = fmaxf(acc[rb][0][jj] + b10, 0.f);
            float v1 = fmaxf(acc[rb][1][jj] + b11, 0.f);
            float s = v0 * w20 + v1 * w21;
            s += __shfl_xor(s, 1); s += __shfl_xor(s, 2);
            s += __shfl_xor(s, 4); s += __shfl_xor(s, 8);
            p[rb][jj] = s;
        }
    if (lr == 0) {
#pragma unroll
        for (int rb = 0; rb < 4; ++rb)
#pragma unroll
            for (int jj = 0; jj < 4; ++jj)
                Red[w * 64 + rb * 16 + hi * 4 + jj] = p[rb][jj];
    }
    __syncthreads();
    if (tid < 64) {
        float gt = Red[tid] + Red[64 + tid] + Red[128 + tid] + Red[192 + tid] + b2[0];
        float m = gt;
#pragma unroll
        for (int off = 32; off >= 1; off >>= 1) m = fmaxf(m, __shfl_xor(m, off));
        float e = expf(gt - m);
        float s = e;
#pragma unroll
        for (int off = 32; off >= 1; off >>= 1) s += __shfl_xor(s, off);
        al[tid] = e / s;
    }
    __syncthreads();
    // weighted pool over fp32 h
    int c = tid & 127, half = tid >> 7;
    float pp = 0.f;
    const float* hbase = h + (size_t)n0 * H;
    for (int j = half * 32; j < half * 32 + 32; ++j)
        pp += al[j] * hbase[(size_t)j * H + c];
    Red[tid] = pp;
    __syncthreads();
    if (tid < 128) pooled[(size_t)g * H + tid] = Red[tid] + Red[128 + tid];
}

// ---------------- K9: global_embedding = [pooled, gf] @ gi_w + gi_b ----------------
__global__ __launch_bounds__(128) void k_final(
    const float* __restrict__ pooled, const float* __restrict__ gfeat,
    const float* __restrict__ gf_w, const float* __restrict__ gf_b,
    const float* __restrict__ gi_w, const float* __restrict__ gi_b,
    float* __restrict__ out)
{
    int g = blockIdx.x, c = threadIdx.x;
    __shared__ float prow[H], gfs[H];
    prow[c] = pooled[(size_t)g * H + c];
    float gv = gf_b[c];
    const float* gr = gfeat + (size_t)g * GF;
#pragma unroll
    for (int k = 0; k < GF; ++k) gv += gr[k] * gf_w[k * H + c];
    gfs[c] = gv;
    __syncthreads();
    float acc = gi_b[c];
    for (int k = 0; k < H; ++k) acc += prow[k] * gi_w[k * H + c];
    for (int k = 0; k < H; ++k) acc += gfs[k] * gi_w[(H + k) * H + c];
    out[(size_t)N_NODES * H + (size_t)g * H + c] = acc;
}

extern "C" void kernel_launch(void* const* d_in, const int* in_sizes, int n_in,
                              void* d_out, int out_size, void* d_ws, size_t ws_size,
                              hipStream_t stream)
{
    const float* x       = (const float*)d_in[0];
    const int*   ei      = (const int*)d_in[1];
    const float* eattr   = (const float*)d_in[2];
    const float* gfeat   = (const float*)d_in[3];
    // d_in[4] = batch (unused; batch[n] == n/64)
    const float* node_w  = (const float*)d_in[5];
    const float* node_b  = (const float*)d_in[6];
    const float* edge_w  = (const float*)d_in[7];
    const float* edge_b  = (const float*)d_in[8];
    const float* rel_w   = (const float*)d_in[9];
    const float* rel_b   = (const float*)d_in[10];
    const float* root_w  = (const float*)d_in[11];
    const float* bn_g    = (const float*)d_in[12];
    const float* bn_b    = (const float*)d_in[13];
    const float* gate_w1 = (const float*)d_in[14];
    const float* gate_b1 = (const float*)d_in[15];
    const float* gate_w2 = (const float*)d_in[16];
    const float* gate_b2 = (const float*)d_in[17];
    const float* gf_w    = (const float*)d_in[18];
    const float* gf_b    = (const float*)d_in[19];
    const float* gi_w    = (const float*)d_in[20];
    const float* gi_b    = (const float*)d_in[21];

    float* h   = (float*)d_out;                          // [N,H] output 0 (written by last layer)
    float* out = (float*)d_out;

    char* wsb = (char*)d_ws;
    size_t off = 0;
    auto take = [&](size_t bytes) -> char* {
        char* r = wsb + off;
        off = (off + bytes + 63) & ~(size_t)63;
        return r;
    };
    unsigned short* h2b  = (unsigned short*)take((size_t)N_NODES * H * 2);
    unsigned short* hb   = (unsigned short*)take((size_t)N_NODES * H * 2);
    unsigned short* aggb = (unsigned short*)take((size_t)N_NODES * H * 2);
    unsigned short* wpck = (unsigned short*)take((size_t)LAYERS * 32768 * 2);
    unsigned short* gwp  = (unsigned short*)take((size_t)16384 * 2);
    float* stats  = (float*)take((size_t)LAYERS * 256 * 4);
    float* pooled = (float*)take((size_t)N_GRAPH * H * 4);
    int*   deg    = (int*)take((size_t)N_NODES * 4);
    int*   rowptr = (int*)take((size_t)(N_NODES + 1) * 4);
    int*   cursor = (int*)take((size_t)N_NODES * 4);
    int*   bsum   = (int*)take((size_t)NB_SCAN * 4);
    int*   boff   = (int*)take((size_t)NB_SCAN * 4);
    uint4* recs   = (uint4*)take((size_t)N_EDGES * 32);  // {src, ea0..4, pad2} per edge
    int*   rowtmp = cursor;   // alias ok (scan3 reads then writes same idx)

    // ---- CSR build + weight repack (once per launch) ----
    hipMemsetAsync(deg, 0, N_NODES * sizeof(int), stream);
    k_deg<<<(N_EDGES + 255) / 256, 256, 0, stream>>>(ei, deg);
    k_scan1<<<NB_SCAN, 256, 0, stream>>>(deg, rowtmp, bsum);
    k_scan2<<<1, 256, 0, stream>>>(bsum, boff);
    k_scan3<<<NB_SCAN, 256, 0, stream>>>(rowtmp, boff, rowptr, cursor);
    k_scatter<<<(N_EDGES + 255) / 256, 256, 0, stream>>>(ei, eattr, cursor, recs);
    k_wpack<<<LAYERS * 64, 64, 0, stream>>>(rel_w, root_w, wpck);
    k_wpack_gate<<<32, 64, 0, stream>>>(gate_w1, gwp);

    k_init_h<<<N_NODES * 32 / 256, 256, 0, stream>>>(x, node_w, node_b, hb);
    hipMemsetAsync(stats, 0, LAYERS * 256 * sizeof(float), stream);

    for (int i = 0; i < LAYERS; ++i) {
        k_agg<<<N_NODES / 8, 256, 0, stream>>>(rowptr, recs, edge_w, edge_b, hb, aggb);
        k_gemm_mfma<<<N_NODES / 64, 256, 0, stream>>>(
            aggb, hb, wpck + (size_t)i * 32768, rel_b + (size_t)i * H,
            h2b, stats + i * 256);
        if (i < LAYERS - 1)
            k_bn_apply<false><<<N_NODES * H / 8 / 256, 256, 0, stream>>>(
                h2b, stats + i * 256, bn_g + (size_t)i * H, bn_b + (size_t)i * H, hb, h);
        else
            k_bn_apply<true><<<N_NODES * H / 8 / 256, 256, 0, stream>>>(
                h2b, stats + i * 256, bn_g + (size_t)i * H, bn_b + (size_t)i * H, hb, h);
    }

    k_gate_pool<<<N_GRAPH, 256, 0, stream>>>(hb, h, gwp, gate_b1, gate_w2, gate_b2, pooled);
    k_final<<<N_GRAPH, H, 0, stream>>>(pooled, gfeat, gf_w, gf_b, gi_w, gi_b, out);
}